// Round 10
// baseline (842.881 us; speedup 1.0000x reference)
//
#include <hip/hip_runtime.h>
#include <math.h>

#define BN_EPS 1e-5f

namespace {

constexpr int Bb = 32;   // batch
constexpr int Cc = 512;  // channels
constexpr int Nn = 1024; // spatial (H*W)
constexpr int Ee = 1024; // embed

typedef __attribute__((ext_vector_type(8))) short short8;
typedef __attribute__((ext_vector_type(4))) float f32x4;
typedef __attribute__((ext_vector_type(4))) unsigned short ushort4_t;

struct bfpair { unsigned short h, l; };

__device__ __forceinline__ unsigned short bf16_rne(float v) {
  unsigned u = __builtin_bit_cast(unsigned, v);
  unsigned r = u + 0x7FFFu + ((u >> 16) & 1u);
  return (unsigned short)(r >> 16);
}
__device__ __forceinline__ float bf16_to_f(unsigned short h) {
  unsigned u = ((unsigned)h) << 16;
  return __builtin_bit_cast(float, u);
}
__device__ __forceinline__ bfpair split_bf(float v) {
  bfpair p;
  p.h = bf16_rne(v);
  p.l = bf16_rne(v - bf16_to_f(p.h));
  return p;
}

__device__ __forceinline__ void gll16(const void* g, void* l) {
  __builtin_amdgcn_global_load_lds(
      (const __attribute__((address_space(1))) void*)g,
      (__attribute__((address_space(3))) void*)l, 16, 0, 0);
}

// all three BN scale/shift pairs in one launch -> hdr[6][1024]
__global__ __launch_bounds__(256) void prep3(
    const float* __restrict__ qg, const float* __restrict__ qb,
    const float* __restrict__ qm, const float* __restrict__ qv,
    const float* __restrict__ kg, const float* __restrict__ kb,
    const float* __restrict__ km, const float* __restrict__ kv,
    const float* __restrict__ vg, const float* __restrict__ vb,
    const float* __restrict__ vm, const float* __restrict__ vv,
    float* __restrict__ hdr) {
  int i = blockIdx.x * blockDim.x + threadIdx.x;
  if (i < 1024) {
    float inv, sc;
    inv = rsqrtf(qv[i] + BN_EPS); sc = qg[i] * inv;
    hdr[i] = sc;          hdr[1024 + i] = qb[i] - qm[i] * sc;
    inv = rsqrtf(kv[i] + BN_EPS); sc = kg[i] * inv;
    hdr[2048 + i] = sc;   hdr[3072 + i] = kb[i] - km[i] * sc;
    inv = rsqrtf(vv[i] + BN_EPS); sc = vg[i] * inv;
    hdr[4096 + i] = sc;   hdr[5120 + i] = vb[i] - vm[i] * sc;
  }
}

// plain f32 -> hi/lo bf16 split (weights)
__global__ __launch_bounds__(256) void convert_w(
    const float* __restrict__ wsrc, unsigned short* __restrict__ wh,
    unsigned short* __restrict__ wl, long total4) {
  for (long i = (long)blockIdx.x * 256 + threadIdx.x; i < total4; i += (long)gridDim.x * 256) {
    float4 v = ((const float4*)wsrc)[i];
    bfpair p0 = split_bf(v.x), p1 = split_bf(v.y), p2 = split_bf(v.z), p3 = split_bf(v.w);
    ushort4_t hv, lv;
    hv.x = p0.h; hv.y = p1.h; hv.z = p2.h; hv.w = p3.h;
    lv.x = p0.l; lv.y = p1.l; lv.z = p2.l; lv.w = p3.l;
    *(ushort4_t*)&wh[i * 4] = hv;
    *(ushort4_t*)&wl[i * 4] = lv;
  }
}

// One x pass -> yq, yk (ws) and yv (d_out batch slots), all split hi/lo bf16.
__global__ __launch_bounds__(256) void convert_y3(
    const float* __restrict__ x, const float* __restrict__ hdr,
    unsigned short* __restrict__ yqh, unsigned short* __restrict__ yql,
    unsigned short* __restrict__ ykh, unsigned short* __restrict__ ykl,
    unsigned short* __restrict__ dout_us, long b0, long total4) {
  const float* sq = hdr;        const float* tq = hdr + 1024;
  const float* sk = hdr + 2048; const float* tk = hdr + 3072;
  const float* sv = hdr + 4096; const float* tv = hdr + 5120;
  for (long i = (long)blockIdx.x * 256 + threadIdx.x; i < total4; i += (long)gridDim.x * 256) {
    float4 v = ((const float4*)x)[i];
    int n4 = (int)(i & 255);
    float4 a, b;
    ushort4_t hv, lv;
    // q
    a = ((const float4*)sq)[n4]; b = ((const float4*)tq)[n4];
    {
      bfpair p0 = split_bf(fmaxf(fmaf(v.x, a.x, b.x), 0.f));
      bfpair p1 = split_bf(fmaxf(fmaf(v.y, a.y, b.y), 0.f));
      bfpair p2 = split_bf(fmaxf(fmaf(v.z, a.z, b.z), 0.f));
      bfpair p3 = split_bf(fmaxf(fmaf(v.w, a.w, b.w), 0.f));
      hv.x = p0.h; hv.y = p1.h; hv.z = p2.h; hv.w = p3.h;
      lv.x = p0.l; lv.y = p1.l; lv.z = p2.l; lv.w = p3.l;
      *(ushort4_t*)&yqh[i * 4] = hv; *(ushort4_t*)&yql[i * 4] = lv;
    }
    // k
    a = ((const float4*)sk)[n4]; b = ((const float4*)tk)[n4];
    {
      bfpair p0 = split_bf(fmaxf(fmaf(v.x, a.x, b.x), 0.f));
      bfpair p1 = split_bf(fmaxf(fmaf(v.y, a.y, b.y), 0.f));
      bfpair p2 = split_bf(fmaxf(fmaf(v.z, a.z, b.z), 0.f));
      bfpair p3 = split_bf(fmaxf(fmaf(v.w, a.w, b.w), 0.f));
      hv.x = p0.h; hv.y = p1.h; hv.z = p2.h; hv.w = p3.h;
      lv.x = p0.l; lv.y = p1.l; lv.z = p2.l; lv.w = p3.l;
      *(ushort4_t*)&ykh[i * 4] = hv; *(ushort4_t*)&ykl[i * 4] = lv;
    }
    // v -> d_out slot (b0+g): hi[524288] | lo[524288]
    a = ((const float4*)sv)[n4]; b = ((const float4*)tv)[n4];
    {
      bfpair p0 = split_bf(fmaxf(fmaf(v.x, a.x, b.x), 0.f));
      bfpair p1 = split_bf(fmaxf(fmaf(v.y, a.y, b.y), 0.f));
      bfpair p2 = split_bf(fmaxf(fmaf(v.z, a.z, b.z), 0.f));
      bfpair p3 = split_bf(fmaxf(fmaf(v.w, a.w, b.w), 0.f));
      hv.x = p0.h; hv.y = p1.h; hv.z = p2.h; hv.w = p3.h;
      lv.x = p0.l; lv.y = p1.l; lv.z = p2.l; lv.w = p3.l;
      long g = i >> 17;
      long local = i & 131071;
      unsigned short* slot = dout_us + (b0 + g) * 1048576L;
      *(ushort4_t*)&slot[local * 4] = hv;
      *(ushort4_t*)&slot[524288 + local * 4] = lv;
    }
  }
}

#define MFMA_BF16 __builtin_amdgcn_mfma_f32_16x16x32_bf16

// one phase: read A frags I0,I0+1 (hi/lo), 24 MFMA against resident B frags.
#define PHASE_PAIR(I0)                                                        \
  {                                                                           \
    short8 ah0 = *(const short8*)&sA[cur][0][wr * WH + (I0) * 16 + fr][kq];   \
    short8 al0 = *(const short8*)&sA[cur][1][wr * WH + (I0) * 16 + fr][kq];   \
    short8 ah1 = *(const short8*)&sA[cur][0][wr * WH + (I0 + 1) * 16 + fr][kq]; \
    short8 al1 = *(const short8*)&sA[cur][1][wr * WH + (I0 + 1) * 16 + fr][kq]; \
    __builtin_amdgcn_s_setprio(1);                                            \
    _Pragma("unroll")                                                         \
    for (int j = 0; j < 4; ++j) {                                             \
      acc[I0][j]     = MFMA_BF16(ah0, bh[j], acc[I0][j], 0, 0, 0);            \
      acc[I0][j]     = MFMA_BF16(ah0, bl[j], acc[I0][j], 0, 0, 0);            \
      acc[I0][j]     = MFMA_BF16(al0, bh[j], acc[I0][j], 0, 0, 0);            \
      acc[I0 + 1][j] = MFMA_BF16(ah1, bh[j], acc[I0 + 1][j], 0, 0, 0);        \
      acc[I0 + 1][j] = MFMA_BF16(ah1, bl[j], acc[I0 + 1][j], 0, 0, 0);        \
      acc[I0 + 1][j] = MFMA_BF16(al1, bh[j], acc[I0 + 1][j], 0, 0, 0);        \
    }                                                                         \
    __builtin_amdgcn_s_setprio(0);                                            \
  }

// ---------------------------------------------------------------------------
// Phase-split pipelined split-bf16 NT GEMM, 512 threads / 8 waves (2x4), BK=32.
// BM=256: wave tile 128x64, LDS 128 KiB dbuf, 8 gll16/thread/tile, 4 phases.
// BM=128: wave tile  64x64, LDS  96 KiB dbuf, 6 gll16/thread/tile, 2 phases.
// Per K-step: {partial STAGE -> counted vmcnt -> barrier} then phases of
// {2 A-frag reads -> setprio 24-MFMA -> barrier}; B frags read once, resident.
// Remaining STAGE in phase 1. lgkmcnt(0) before final barrier guards the
// buffer overwrite (next step stages into buf[cur]).
// Chunk-XOR LDS swizzle as validated r5-r9 (0 conflicts).
// B operand selected by m0 (>= msel -> B1) for stacked-[Wq;Wk] projection.
// ---------------------------------------------------------------------------
template<bool SPLIT, bool MFIRST, int BM>
__global__ __launch_bounds__(512, 2) void gemm3p(
    const unsigned short* __restrict__ Ah, const unsigned short* __restrict__ Al,
    long ldA, long bsA,
    const unsigned short* __restrict__ Bh0, const unsigned short* __restrict__ Bl0,
    const unsigned short* __restrict__ Bh1, const unsigned short* __restrict__ Bl1,
    int msel, long ldB, long bsB,
    float* __restrict__ Cf, unsigned short* __restrict__ Chi, unsigned short* __restrict__ Clo,
    long ldC, long bsC, int K, float alpha, int g0, int g1) {
  constexpr int WH = BM / 2;   // wave tile rows
  constexpr int AF = WH / 16;  // A fragments per wave (8 or 4)
  __shared__ unsigned short sA[2][2][BM][32];
  __shared__ unsigned short sB[2][2][256][32];

  const int nb = gridDim.x;
  int f = blockIdx.x;
  if ((nb & 7) == 0) f = (f & 7) * (nb >> 3) + (f >> 3);  // XCD-chunked swizzle
  const int i0 = f % g0, i1 = (f / g0) % g1;
  const long zb = f / (g0 * g1);
  const int m0 = (MFIRST ? i0 : i1) * BM;
  const int n0 = (MFIRST ? i1 : i0) * 256;

  const int t = threadIdx.x, lane = t & 63, w = t >> 6;  // w: 0..7
  const int wr = w >> 2, wc = w & 3;                     // wave tile (wr, wc)
  const int sr  = lane >> 2;
  const int skc = (((lane & 3) ^ ((lane >> 3) & 3)) * 8);      // permuted global col
  const int fr = lane & 15;
  const int kq = ((((lane >> 4) & 3) ^ ((fr >> 1) & 3)) * 8);  // swizzled read col

  const unsigned short* Bh = (m0 >= msel) ? Bh1 : Bh0;
  const unsigned short* Bl = (m0 >= msel) ? Bl1 : Bl0;

  // staging pointers
  const int aw = w & 3, ahl = w >> 2;  // BM==128 mapping
  const unsigned short* a0;
  const unsigned short* a1 = nullptr;
  if (BM == 256) {
    a0 = Ah + zb * bsA + (long)(m0 + w * 32 + sr) * ldA + skc;
    a1 = Al + zb * bsA + (long)(m0 + w * 32 + sr) * ldA + skc;
  } else {
    a0 = (ahl ? Al : Ah) + zb * bsA + (long)(m0 + aw * 32 + sr) * ldA + skc;
  }
  const unsigned short* b0 = Bh + zb * bsB + (long)(n0 + w * 32 + sr) * ldB + skc;
  const unsigned short* b1 = Bl + zb * bsB + (long)(n0 + w * 32 + sr) * ldB + skc;
  const long a16 = 16 * ldA, b16 = 16 * ldB;

  // STAGE split: portion 0 (issued at step open, before counted vmcnt)
  //              portion 1 (issued in phase 1)
  // loads/thread/tile: BM256 -> 4+4, BM128 -> 3+3
  auto STAGE_0 = [&](int buf) {
    if constexpr (BM == 256) {
      gll16(b0, &sB[buf][0][w * 32][0]);  gll16(b0 + b16, &sB[buf][0][w * 32 + 16][0]);
      gll16(b1, &sB[buf][1][w * 32][0]);  gll16(b1 + b16, &sB[buf][1][w * 32 + 16][0]);
      b0 += 32; b1 += 32;
    } else {
      gll16(a0, &sA[buf][ahl][aw * 32][0]);
      gll16(b0, &sB[buf][0][w * 32][0]);
      gll16(b1, &sB[buf][1][w * 32][0]);
    }
  };
  auto STAGE_1 = [&](int buf) {
    if constexpr (BM == 256) {
      gll16(a0, &sA[buf][0][w * 32][0]);  gll16(a0 + a16, &sA[buf][0][w * 32 + 16][0]);
      gll16(a1, &sA[buf][1][w * 32][0]);  gll16(a1 + a16, &sA[buf][1][w * 32 + 16][0]);
      a0 += 32; a1 += 32;
    } else {
      gll16(a0 + a16, &sA[buf][ahl][aw * 32 + 16][0]);
      gll16(b0 + b16, &sB[buf][0][w * 32 + 16][0]);
      gll16(b1 + b16, &sB[buf][1][w * 32 + 16][0]);
      a0 += 32; b0 += 32; b1 += 32;
    }
  };

  f32x4 acc[AF][4] = {};
  const int nt = K >> 5;

  STAGE_0(0);
  STAGE_1(0);
  int cur = 0;

  for (int it = 0; it < nt; ++it) {
    const bool pf = (it + 1 < nt);
    // ---- step open: partial prefetch, counted wait, tile-visible barrier ----
    if (pf) {
      STAGE_0(cur ^ 1);
      if constexpr (BM == 256) asm volatile("s_waitcnt vmcnt(4)" ::: "memory");
      else                     asm volatile("s_waitcnt vmcnt(3)" ::: "memory");
    } else {
      asm volatile("s_waitcnt vmcnt(0)" ::: "memory");
    }
    asm volatile("s_barrier" ::: "memory");   // buf[cur] staged by all waves

    // B fragments: read once, resident across phases
    short8 bh[4], bl[4];
#pragma unroll
    for (int j = 0; j < 4; ++j) {
      bh[j] = *(const short8*)&sB[cur][0][wc * 64 + j * 16 + fr][kq];
      bl[j] = *(const short8*)&sB[cur][1][wc * 64 + j * 16 + fr][kq];
    }

    // ---- phase 0 ----
    PHASE_PAIR(0)
    asm volatile("s_barrier" ::: "memory");
    // ---- phase 1 (+ remaining prefetch) ----
    if (pf) STAGE_1(cur ^ 1);
    PHASE_PAIR(2)
    if constexpr (BM == 256) {
      asm volatile("s_barrier" ::: "memory");
      // ---- phase 2 ----
      PHASE_PAIR(4)
      asm volatile("s_barrier" ::: "memory");
      // ---- phase 3 ----
      PHASE_PAIR(6)
    }
    asm volatile("s_waitcnt lgkmcnt(0)" ::: "memory");  // buf[cur] reads done
    asm volatile("s_barrier" ::: "memory");             // all waves done
    cur ^= 1;
  }

  // epilogue: C/D layout col = lane&15, row = (lane>>4)*4 + reg  [verified m89/m91]
  const int rb = ((lane >> 4) & 3) * 4;
#pragma unroll
  for (int i = 0; i < AF; ++i)
#pragma unroll
    for (int j = 0; j < 4; ++j) {
      long col = n0 + wc * 64 + j * 16 + fr;
#pragma unroll
      for (int v = 0; v < 4; ++v) {
        long row = m0 + wr * WH + i * 16 + rb + v;
        float val = acc[i][j][v] * alpha;
        long idx = zb * bsC + row * ldC + col;
        if (SPLIT) {
          bfpair p = split_bf(val);
          Chi[idx] = p.h;
          Clo[idx] = p.l;
        } else {
          Cf[idx] = val;
        }
      }
    }
}

// softmax over rows of 1024 f32, writes P split as hi[1024]|lo[1024] ushorts in place.
__global__ __launch_bounds__(256) void softmax_rows(float* __restrict__ S) {
  long row = blockIdx.x;
  float* p = S + row * 1024;
  int t = threadIdx.x;
  float4 v = *(float4*)(p + 4 * t);
  float mx = fmaxf(fmaxf(v.x, v.y), fmaxf(v.z, v.w));
#pragma unroll
  for (int i = 1; i < 64; i <<= 1) mx = fmaxf(mx, __shfl_xor(mx, i));
  __shared__ float redm[4];
  __shared__ float reds[4];
  int wave = t >> 6, lane = t & 63;
  if (lane == 0) redm[wave] = mx;
  __syncthreads();
  mx = fmaxf(fmaxf(redm[0], redm[1]), fmaxf(redm[2], redm[3]));
  float e0 = expf(v.x - mx), e1 = expf(v.y - mx);
  float e2 = expf(v.z - mx), e3 = expf(v.w - mx);
  float sum = (e0 + e1) + (e2 + e3);
#pragma unroll
  for (int i = 1; i < 64; i <<= 1) sum += __shfl_xor(sum, i);
  if (lane == 0) reds[wave] = sum;
  __syncthreads();
  sum = (reds[0] + reds[1]) + (reds[2] + reds[3]);
  float inv = 1.0f / sum;
  bfpair p0 = split_bf(e0 * inv), p1 = split_bf(e1 * inv);
  bfpair p2 = split_bf(e2 * inv), p3 = split_bf(e3 * inv);
  ushort4_t hv, lv;
  hv.x = p0.h; hv.y = p1.h; hv.z = p2.h; hv.w = p3.h;
  lv.x = p0.l; lv.y = p1.l; lv.z = p2.l; lv.w = p3.l;
  unsigned short* ph = (unsigned short*)p;
  *(ushort4_t*)&ph[4 * t] = hv;
  *(ushort4_t*)&ph[1024 + 4 * t] = lv;
}

}  // namespace

extern "C" void kernel_launch(void* const* d_in, const int* in_sizes, int n_in,
                              void* d_out, int out_size, void* d_ws, size_t ws_size,
                              hipStream_t stream) {
  const float* x  = (const float*)d_in[0];
  const float* qg = (const float*)d_in[1];
  const float* qb = (const float*)d_in[2];
  const float* qm = (const float*)d_in[3];
  const float* qv = (const float*)d_in[4];
  const float* kg = (const float*)d_in[5];
  const float* kb = (const float*)d_in[6];
  const float* km = (const float*)d_in[7];
  const float* kv = (const float*)d_in[8];
  const float* vg = (const float*)d_in[9];
  const float* vb = (const float*)d_in[10];
  const float* vm = (const float*)d_in[11];
  const float* vv = (const float*)d_in[12];
  const float* Wq = (const float*)d_in[13];
  const float* Wk = (const float*)d_in[14];
  const float* Wv = (const float*)d_in[15];
  const float* Wp = (const float*)d_in[16];

  // ---- workspace ----
  // fixed: hdr 64 KiB | WQK hi/lo 8 MiB | Wv hi/lo 4 | Wp hi/lo 4  = ~16 MiB
  // per batch: yq+yk hi/lo 4 MiB | QK hi/lo 4 MiB | S 4 MiB        = 12 MiB
  // yv hi/lo lives in the batch's d_out slot (2 MiB); Vt overwrites yq/yk;
  // Ot overwrites QK; out overwrites the d_out slot.  G=16 -> 208 MiB.
  const size_t wFix = 65536 + 16UL * 1024 * 1024;
  const size_t perB = 12UL * 1024 * 1024;
  int G = 32;
  while (G > 1 && wFix + (size_t)G * perB > ws_size) G >>= 1;

  char* ws = (char*)d_ws;
  float* hdr = (float*)ws;

  const long WE = 1024L * 1024;
  unsigned short* WQKh = (unsigned short*)(ws + 65536);  // [2048][1024]
  unsigned short* WQKl = WQKh + 2 * WE;
  unsigned short* Wvh  = WQKl + 2 * WE;
  unsigned short* Wvl  = Wvh + WE;
  unsigned short* Wph  = Wvl + WE;
  unsigned short* Wpl  = Wph + WE;

  const long YB = 524288;  // elements/batch of y arrays ([C][N])
  unsigned short* yqh = Wpl + WE;
  unsigned short* yql = yqh + (long)G * YB;
  unsigned short* ykh = yql + (long)G * YB;
  unsigned short* ykl = ykh + (long)G * YB;
  const long QKBS = 1048576;  // [2048][512] per batch
  unsigned short* QKh = ykl + (long)G * YB;
  unsigned short* QKl = QKh + (long)G * QKBS;
  float* S = (float*)(QKl + (long)G * QKBS);  // [G][1024][1024]

  unsigned short* dout_us = (unsigned short*)d_out;  // per batch: yv hi|lo slot

  dim3 blk(256);
  const int BIG = 1 << 30;

  prep3<<<dim3(4), blk, 0, stream>>>(qg, qb, qm, qv, kg, kb, km, kv, vg, vb, vm, vv, hdr);

  const long W4 = WE / 4;
  convert_w<<<dim3(1024), blk, 0, stream>>>(Wq, WQKh, WQKl, W4);
  convert_w<<<dim3(1024), blk, 0, stream>>>(Wk, WQKh + WE, WQKl + WE, W4);
  convert_w<<<dim3(1024), blk, 0, stream>>>(Wv, Wvh, Wvl, W4);
  convert_w<<<dim3(1024), blk, 0, stream>>>(Wp, Wph, Wpl, W4);

  for (int b0 = 0; b0 < Bb; b0 += G) {
    const float* xg = x + (size_t)b0 * Cc * Nn;

    // 1) BN+ReLU+split: yq,yk -> ws; yv -> d_out slots
    convert_y3<<<dim3(2048), blk, 0, stream>>>(
        xg, hdr, yqh, yql, ykh, ykl, dout_us, b0, (long)G * 131072);

    // 2) [Q;K] = [Wq;Wk] x y: M=2048, N=512, K=1024; BM256, m-fastest (y-panel reuse)
    gemm3p<true, true, 256><<<dim3(8 * 2 * G), dim3(512), 0, stream>>>(
        WQKh, WQKl, Nn, 0L,
        yqh, yql, ykh, ykl, 1024, Nn, YB,
        nullptr, QKh, QKl, Cc, QKBS, Nn, 1.0f, 8, 2);

    // 3) S = Q K^T / 32: M=1024, N=1024, K=512; BM256
    gemm3p<false, false, 256><<<dim3(4 * 4 * G), dim3(512), 0, stream>>>(
        QKh, QKl, Cc, QKBS,
        QKh + 524288, QKl + 524288, nullptr, nullptr, BIG, Cc, QKBS,
        S, nullptr, nullptr, Ee, 1048576L, Cc, 0.03125f, 4, 4);

    // 4) softmax rows -> P hi/lo packed in S
    softmax_rows<<<dim3(G * Ee), blk, 0, stream>>>(S);

    // 5) Vt[c][e] = sum_n yv[c][n] Wv[e][n]: M=512, N=1024, K=1024; BM128
    gemm3p<true, false, 128><<<dim3(4 * 4 * G), dim3(512), 0, stream>>>(
        dout_us + (long)b0 * 1048576, dout_us + (long)b0 * 1048576 + 524288, Nn, 1048576L,
        Wvh, Wvl, nullptr, nullptr, BIG, Nn, 0L,
        nullptr, yqh, yql, Ee, YB, Nn, 1.0f, 4, 4);

    // 6) Ot[c][e] = sum_f Vt[c][f] P[e][f]: M=512, N=1024, K=1024; BM128
    gemm3p<true, false, 128><<<dim3(4 * 4 * G), dim3(512), 0, stream>>>(
        yqh, yql, Ee, YB,
        (unsigned short*)S, (unsigned short*)S + 1024, nullptr, nullptr, BIG,
        2L * Ee, 2097152L,
        nullptr, QKh, QKl, Ee, QKBS, Ee, 1.0f, 4, 4);

    // 7) out[c][n] = sum_e Ot[c][e] Wp[n][e]: M=512, N=1024, K=1024; BM128, f32 out
    gemm3p<false, false, 128><<<dim3(4 * 4 * G), dim3(512), 0, stream>>>(
        QKh, QKl, Ee, QKBS,
        Wph, Wpl, nullptr, nullptr, BIG, Ee, 0L,
        (float*)d_out + (size_t)b0 * Cc * Nn, nullptr, nullptr,
        Nn, (long)Cc * Nn, Ee, 1.0f, 4, 4);
  }
}

// Round 11
// 792.715 us; speedup vs baseline: 1.0633x; 1.0633x over previous
//
#include <hip/hip_runtime.h>
#include <math.h>

#define BN_EPS 1e-5f

namespace {

constexpr int Bb = 32;   // batch
constexpr int Cc = 512;  // channels
constexpr int Nn = 1024; // spatial (H*W)
constexpr int Ee = 1024; // embed

typedef __attribute__((ext_vector_type(8))) short short8;
typedef __attribute__((ext_vector_type(16))) float f32x16;
typedef __attribute__((ext_vector_type(4))) unsigned short ushort4_t;

struct bfpair { unsigned short h, l; };

__device__ __forceinline__ unsigned short bf16_rne(float v) {
  unsigned u = __builtin_bit_cast(unsigned, v);
  unsigned r = u + 0x7FFFu + ((u >> 16) & 1u);
  return (unsigned short)(r >> 16);
}
__device__ __forceinline__ float bf16_to_f(unsigned short h) {
  unsigned u = ((unsigned)h) << 16;
  return __builtin_bit_cast(float, u);
}
__device__ __forceinline__ bfpair split_bf(float v) {
  bfpair p;
  p.h = bf16_rne(v);
  p.l = bf16_rne(v - bf16_to_f(p.h));
  return p;
}

__device__ __forceinline__ void gll16(const void* g, void* l) {
  __builtin_amdgcn_global_load_lds(
      (const __attribute__((address_space(1))) void*)g,
      (__attribute__((address_space(3))) void*)l, 16, 0, 0);
}

// all three BN scale/shift pairs in one launch -> hdr[6][1024]
__global__ __launch_bounds__(256) void prep3(
    const float* __restrict__ qg, const float* __restrict__ qb,
    const float* __restrict__ qm, const float* __restrict__ qv,
    const float* __restrict__ kg, const float* __restrict__ kb,
    const float* __restrict__ km, const float* __restrict__ kv,
    const float* __restrict__ vg, const float* __restrict__ vb,
    const float* __restrict__ vm, const float* __restrict__ vv,
    float* __restrict__ hdr) {
  int i = blockIdx.x * blockDim.x + threadIdx.x;
  if (i < 1024) {
    float inv, sc;
    inv = rsqrtf(qv[i] + BN_EPS); sc = qg[i] * inv;
    hdr[i] = sc;          hdr[1024 + i] = qb[i] - qm[i] * sc;
    inv = rsqrtf(kv[i] + BN_EPS); sc = kg[i] * inv;
    hdr[2048 + i] = sc;   hdr[3072 + i] = kb[i] - km[i] * sc;
    inv = rsqrtf(vv[i] + BN_EPS); sc = vg[i] * inv;
    hdr[4096 + i] = sc;   hdr[5120 + i] = vb[i] - vm[i] * sc;
  }
}

// plain f32 -> hi/lo bf16 split (weights)
__global__ __launch_bounds__(256) void convert_w(
    const float* __restrict__ wsrc, unsigned short* __restrict__ wh,
    unsigned short* __restrict__ wl, long total4) {
  for (long i = (long)blockIdx.x * 256 + threadIdx.x; i < total4; i += (long)gridDim.x * 256) {
    float4 v = ((const float4*)wsrc)[i];
    bfpair p0 = split_bf(v.x), p1 = split_bf(v.y), p2 = split_bf(v.z), p3 = split_bf(v.w);
    ushort4_t hv, lv;
    hv.x = p0.h; hv.y = p1.h; hv.z = p2.h; hv.w = p3.h;
    lv.x = p0.l; lv.y = p1.l; lv.z = p2.l; lv.w = p3.l;
    *(ushort4_t*)&wh[i * 4] = hv;
    *(ushort4_t*)&wl[i * 4] = lv;
  }
}

// One x pass -> yq, yk (ws) and yv (d_out batch slots), all split hi/lo bf16.
__global__ __launch_bounds__(256) void convert_y3(
    const float* __restrict__ x, const float* __restrict__ hdr,
    unsigned short* __restrict__ yqh, unsigned short* __restrict__ yql,
    unsigned short* __restrict__ ykh, unsigned short* __restrict__ ykl,
    unsigned short* __restrict__ dout_us, long b0, long total4) {
  const float* sq = hdr;        const float* tq = hdr + 1024;
  const float* sk = hdr + 2048; const float* tk = hdr + 3072;
  const float* sv = hdr + 4096; const float* tv = hdr + 5120;
  for (long i = (long)blockIdx.x * 256 + threadIdx.x; i < total4; i += (long)gridDim.x * 256) {
    float4 v = ((const float4*)x)[i];
    int n4 = (int)(i & 255);
    float4 a, b;
    ushort4_t hv, lv;
    // q
    a = ((const float4*)sq)[n4]; b = ((const float4*)tq)[n4];
    {
      bfpair p0 = split_bf(fmaxf(fmaf(v.x, a.x, b.x), 0.f));
      bfpair p1 = split_bf(fmaxf(fmaf(v.y, a.y, b.y), 0.f));
      bfpair p2 = split_bf(fmaxf(fmaf(v.z, a.z, b.z), 0.f));
      bfpair p3 = split_bf(fmaxf(fmaf(v.w, a.w, b.w), 0.f));
      hv.x = p0.h; hv.y = p1.h; hv.z = p2.h; hv.w = p3.h;
      lv.x = p0.l; lv.y = p1.l; lv.z = p2.l; lv.w = p3.l;
      *(ushort4_t*)&yqh[i * 4] = hv; *(ushort4_t*)&yql[i * 4] = lv;
    }
    // k
    a = ((const float4*)sk)[n4]; b = ((const float4*)tk)[n4];
    {
      bfpair p0 = split_bf(fmaxf(fmaf(v.x, a.x, b.x), 0.f));
      bfpair p1 = split_bf(fmaxf(fmaf(v.y, a.y, b.y), 0.f));
      bfpair p2 = split_bf(fmaxf(fmaf(v.z, a.z, b.z), 0.f));
      bfpair p3 = split_bf(fmaxf(fmaf(v.w, a.w, b.w), 0.f));
      hv.x = p0.h; hv.y = p1.h; hv.z = p2.h; hv.w = p3.h;
      lv.x = p0.l; lv.y = p1.l; lv.z = p2.l; lv.w = p3.l;
      *(ushort4_t*)&ykh[i * 4] = hv; *(ushort4_t*)&ykl[i * 4] = lv;
    }
    // v -> d_out slot (b0+g): hi[524288] | lo[524288]
    a = ((const float4*)sv)[n4]; b = ((const float4*)tv)[n4];
    {
      bfpair p0 = split_bf(fmaxf(fmaf(v.x, a.x, b.x), 0.f));
      bfpair p1 = split_bf(fmaxf(fmaf(v.y, a.y, b.y), 0.f));
      bfpair p2 = split_bf(fmaxf(fmaf(v.z, a.z, b.z), 0.f));
      bfpair p3 = split_bf(fmaxf(fmaf(v.w, a.w, b.w), 0.f));
      hv.x = p0.h; hv.y = p1.h; hv.z = p2.h; hv.w = p3.h;
      lv.x = p0.l; lv.y = p1.l; lv.z = p2.l; lv.w = p3.l;
      long g = i >> 17;
      long local = i & 131071;
      unsigned short* slot = dout_us + (b0 + g) * 1048576L;
      *(ushort4_t*)&slot[local * 4] = hv;
      *(ushort4_t*)&slot[524288 + local * 4] = lv;
    }
  }
}

#define MFMA32 __builtin_amdgcn_mfma_f32_32x32x16_bf16

// ---------------------------------------------------------------------------
// Pipelined split-bf16 NT GEMM, 512 threads / 8 waves (2x4), BK=32,
// mfma_f32_32x32x16_bf16 (r11: shape switch; −17% matrix-pipe cycles, half
// the MFMA instruction count vs 16x16x32; LDS traffic unchanged).
// BM=256: wave tile 128x64 (4x2 frags of 32x32), LDS 128 KiB dbuf, 8 gll16/stage.
// BM=128: wave tile  64x64 (2x2 frags),          LDS  96 KiB dbuf, 6 gll16/stage.
// Schedule = r7/r9 (validated): vmcnt(N) counted -> barrier -> kh0 frag reads
// -> MFMA kh0 -> kh1 frag reads -> lgkmcnt(0) -> barrier -> STAGE(t+2) ->
// MFMA kh1.  acc += Ah*Bh + Ah*Bl + Al*Bh.
// Fragment layout: A,B both row x K (row=lane&31, kchunk=lane>>5) from
// identically swizzled LDS tiles -> D = A*B^T (symmetry validated r4-r9).
// C/D: col=lane&31, row=(reg&3)+8*(reg>>2)+4*(lane>>5)  [m74/m101].
// Chunk-XOR LDS swizzle as validated r5-r9 (0 conflicts).
// B operand selected by m0 (>= msel -> B1) for stacked-[Wq;Wk] projection.
// ---------------------------------------------------------------------------
template<bool SPLIT, bool MFIRST, int BM>
__global__ __launch_bounds__(512, 2) void gemm3p(
    const unsigned short* __restrict__ Ah, const unsigned short* __restrict__ Al,
    long ldA, long bsA,
    const unsigned short* __restrict__ Bh0, const unsigned short* __restrict__ Bl0,
    const unsigned short* __restrict__ Bh1, const unsigned short* __restrict__ Bl1,
    int msel, long ldB, long bsB,
    float* __restrict__ Cf, unsigned short* __restrict__ Chi, unsigned short* __restrict__ Clo,
    long ldC, long bsC, int K, float alpha, int g0, int g1) {
  constexpr int WH = BM / 2;   // wave tile rows
  constexpr int AB = WH / 32;  // A 32-row blocks per wave (4 or 2)
  __shared__ unsigned short sA[2][2][BM][32];
  __shared__ unsigned short sB[2][2][256][32];

  const int nb = gridDim.x;
  int f = blockIdx.x;
  if ((nb & 7) == 0) f = (f & 7) * (nb >> 3) + (f >> 3);  // XCD-chunked swizzle
  const int i0 = f % g0, i1 = (f / g0) % g1;
  const long zb = f / (g0 * g1);
  const int m0 = (MFIRST ? i0 : i1) * BM;
  const int n0 = (MFIRST ? i1 : i0) * 256;

  const int t = threadIdx.x, lane = t & 63, w = t >> 6;  // w: 0..7
  const int wr = w >> 2, wc = w & 3;                     // wave tile (wr, wc)
  const int sr  = lane >> 2;
  const int skc = (((lane & 3) ^ ((lane >> 3) & 3)) * 8);  // permuted global col
  const int r32 = lane & 31;                               // fragment row/col
  const int l5  = lane >> 5;                               // fragment k-sub
  const int cs  = (r32 >> 1) & 3;                          // row swizzle bits

  const unsigned short* Bh = (m0 >= msel) ? Bh1 : Bh0;
  const unsigned short* Bl = (m0 >= msel) ? Bl1 : Bl0;

  // staging pointers
  const int aw = w & 3, ahl = w >> 2;  // BM==128 mapping
  const unsigned short* a0;
  const unsigned short* a1 = nullptr;
  if (BM == 256) {
    a0 = Ah + zb * bsA + (long)(m0 + w * 32 + sr) * ldA + skc;
    a1 = Al + zb * bsA + (long)(m0 + w * 32 + sr) * ldA + skc;
  } else {
    a0 = (ahl ? Al : Ah) + zb * bsA + (long)(m0 + aw * 32 + sr) * ldA + skc;
  }
  const unsigned short* b0 = Bh + zb * bsB + (long)(n0 + w * 32 + sr) * ldB + skc;
  const unsigned short* b1 = Bl + zb * bsB + (long)(n0 + w * 32 + sr) * ldB + skc;
  const long a16 = 16 * ldA, b16 = 16 * ldB;

  // loads per thread per STAGE: BM256 -> 8, BM128 -> 6 (vmcnt depends on this)
  auto STAGE = [&](int buf) {
    if constexpr (BM == 256) {
      gll16(a0, &sA[buf][0][w * 32][0]);  gll16(a0 + a16, &sA[buf][0][w * 32 + 16][0]);
      gll16(a1, &sA[buf][1][w * 32][0]);  gll16(a1 + a16, &sA[buf][1][w * 32 + 16][0]);
      a0 += 32; a1 += 32;
    } else {
      gll16(a0, &sA[buf][ahl][aw * 32][0]);
      gll16(a0 + a16, &sA[buf][ahl][aw * 32 + 16][0]);
      a0 += 32;
    }
    gll16(b0, &sB[buf][0][w * 32][0]);  gll16(b0 + b16, &sB[buf][0][w * 32 + 16][0]);
    gll16(b1, &sB[buf][1][w * 32][0]);  gll16(b1 + b16, &sB[buf][1][w * 32 + 16][0]);
    b0 += 32; b1 += 32;
  };

  f32x16 acc[AB][2] = {};
  const int nt = K >> 5;

  STAGE(0);
  STAGE(1);
  int cur = 0;

  const int kc0 = ((0 + l5) ^ cs) * 8;  // k-half 0 read col (elements)
  const int kc1 = ((2 + l5) ^ cs) * 8;  // k-half 1 read col

  for (int it = 0; it < nt; ++it) {
    if (it + 1 < nt) {
      if constexpr (BM == 256) asm volatile("s_waitcnt vmcnt(8)" ::: "memory");
      else                     asm volatile("s_waitcnt vmcnt(6)" ::: "memory");
    } else {
      asm volatile("s_waitcnt vmcnt(0)" ::: "memory");
    }
    asm volatile("s_barrier" ::: "memory");   // buf[cur] staged by all waves

    // ---- k-half 0: reads + MFMA ----
    short8 bh[2], bl[2], ah[AB], al[AB];
#pragma unroll
    for (int jb = 0; jb < 2; ++jb) {
      bh[jb] = *(const short8*)&sB[cur][0][wc * 64 + jb * 32 + r32][kc0];
      bl[jb] = *(const short8*)&sB[cur][1][wc * 64 + jb * 32 + r32][kc0];
    }
#pragma unroll
    for (int ib = 0; ib < AB; ++ib) {
      ah[ib] = *(const short8*)&sA[cur][0][wr * WH + ib * 32 + r32][kc0];
      al[ib] = *(const short8*)&sA[cur][1][wr * WH + ib * 32 + r32][kc0];
    }
    __builtin_amdgcn_s_setprio(1);
#pragma unroll
    for (int ib = 0; ib < AB; ++ib)
#pragma unroll
      for (int jb = 0; jb < 2; ++jb) {
        acc[ib][jb] = MFMA32(ah[ib], bh[jb], acc[ib][jb], 0, 0, 0);
        acc[ib][jb] = MFMA32(ah[ib], bl[jb], acc[ib][jb], 0, 0, 0);
        acc[ib][jb] = MFMA32(al[ib], bh[jb], acc[ib][jb], 0, 0, 0);
      }
    __builtin_amdgcn_s_setprio(0);

    // ---- k-half 1: reads, then fence + stage, then MFMA ----
    short8 bh1v[2], bl1v[2], ah1v[AB], al1v[AB];
#pragma unroll
    for (int jb = 0; jb < 2; ++jb) {
      bh1v[jb] = *(const short8*)&sB[cur][0][wc * 64 + jb * 32 + r32][kc1];
      bl1v[jb] = *(const short8*)&sB[cur][1][wc * 64 + jb * 32 + r32][kc1];
    }
#pragma unroll
    for (int ib = 0; ib < AB; ++ib) {
      ah1v[ib] = *(const short8*)&sA[cur][0][wr * WH + ib * 32 + r32][kc1];
      al1v[ib] = *(const short8*)&sA[cur][1][wr * WH + ib * 32 + r32][kc1];
    }
    asm volatile("s_waitcnt lgkmcnt(0)" ::: "memory");  // buf[cur] reads done
    asm volatile("s_barrier" ::: "memory");             // all waves done
    if (it + 2 < nt) STAGE(cur);                        // overwrite safe now
    __builtin_amdgcn_s_setprio(1);
#pragma unroll
    for (int ib = 0; ib < AB; ++ib)
#pragma unroll
      for (int jb = 0; jb < 2; ++jb) {
        acc[ib][jb] = MFMA32(ah1v[ib], bh1v[jb], acc[ib][jb], 0, 0, 0);
        acc[ib][jb] = MFMA32(ah1v[ib], bl1v[jb], acc[ib][jb], 0, 0, 0);
        acc[ib][jb] = MFMA32(al1v[ib], bh1v[jb], acc[ib][jb], 0, 0, 0);
      }
    __builtin_amdgcn_s_setprio(0);
    cur ^= 1;
  }

  // epilogue: 32x32 C/D layout col=lane&31, row=(reg&3)+8*(reg>>2)+4*(lane>>5)
  const int rbase = 4 * l5;
#pragma unroll
  for (int ib = 0; ib < AB; ++ib)
#pragma unroll
    for (int jb = 0; jb < 2; ++jb) {
      long col = n0 + wc * 64 + jb * 32 + r32;
#pragma unroll
      for (int r = 0; r < 16; ++r) {
        long row = m0 + wr * WH + ib * 32 + (r & 3) + 8 * (r >> 2) + rbase;
        float val = acc[ib][jb][r] * alpha;
        long idx = zb * bsC + row * ldC + col;
        if (SPLIT) {
          bfpair p = split_bf(val);
          Chi[idx] = p.h;
          Clo[idx] = p.l;
        } else {
          Cf[idx] = val;
        }
      }
    }
}

// softmax over rows of 1024 f32, writes P split as hi[1024]|lo[1024] ushorts in place.
__global__ __launch_bounds__(256) void softmax_rows(float* __restrict__ S) {
  long row = blockIdx.x;
  float* p = S + row * 1024;
  int t = threadIdx.x;
  float4 v = *(float4*)(p + 4 * t);
  float mx = fmaxf(fmaxf(v.x, v.y), fmaxf(v.z, v.w));
#pragma unroll
  for (int i = 1; i < 64; i <<= 1) mx = fmaxf(mx, __shfl_xor(mx, i));
  __shared__ float redm[4];
  __shared__ float reds[4];
  int wave = t >> 6, lane = t & 63;
  if (lane == 0) redm[wave] = mx;
  __syncthreads();
  mx = fmaxf(fmaxf(redm[0], redm[1]), fmaxf(redm[2], redm[3]));
  float e0 = expf(v.x - mx), e1 = expf(v.y - mx);
  float e2 = expf(v.z - mx), e3 = expf(v.w - mx);
  float sum = (e0 + e1) + (e2 + e3);
#pragma unroll
  for (int i = 1; i < 64; i <<= 1) sum += __shfl_xor(sum, i);
  if (lane == 0) reds[wave] = sum;
  __syncthreads();
  sum = (reds[0] + reds[1]) + (reds[2] + reds[3]);
  float inv = 1.0f / sum;
  bfpair p0 = split_bf(e0 * inv), p1 = split_bf(e1 * inv);
  bfpair p2 = split_bf(e2 * inv), p3 = split_bf(e3 * inv);
  ushort4_t hv, lv;
  hv.x = p0.h; hv.y = p1.h; hv.z = p2.h; hv.w = p3.h;
  lv.x = p0.l; lv.y = p1.l; lv.z = p2.l; lv.w = p3.l;
  unsigned short* ph = (unsigned short*)p;
  *(ushort4_t*)&ph[4 * t] = hv;
  *(ushort4_t*)&ph[1024 + 4 * t] = lv;
}

}  // namespace

extern "C" void kernel_launch(void* const* d_in, const int* in_sizes, int n_in,
                              void* d_out, int out_size, void* d_ws, size_t ws_size,
                              hipStream_t stream) {
  const float* x  = (const float*)d_in[0];
  const float* qg = (const float*)d_in[1];
  const float* qb = (const float*)d_in[2];
  const float* qm = (const float*)d_in[3];
  const float* qv = (const float*)d_in[4];
  const float* kg = (const float*)d_in[5];
  const float* kb = (const float*)d_in[6];
  const float* km = (const float*)d_in[7];
  const float* kv = (const float*)d_in[8];
  const float* vg = (const float*)d_in[9];
  const float* vb = (const float*)d_in[10];
  const float* vm = (const float*)d_in[11];
  const float* vv = (const float*)d_in[12];
  const float* Wq = (const float*)d_in[13];
  const float* Wk = (const float*)d_in[14];
  const float* Wv = (const float*)d_in[15];
  const float* Wp = (const float*)d_in[16];

  // ---- workspace ----
  // fixed: hdr 64 KiB | WQK hi/lo 8 MiB | Wv hi/lo 4 | Wp hi/lo 4  = ~16 MiB
  // per batch: yq+yk hi/lo 4 MiB | QK hi/lo 4 MiB | S 4 MiB        = 12 MiB
  // yv hi/lo lives in the batch's d_out slot (2 MiB); Vt overwrites yq/yk;
  // Ot overwrites QK; out overwrites the d_out slot.  G=16 -> 208 MiB.
  const size_t wFix = 65536 + 16UL * 1024 * 1024;
  const size_t perB = 12UL * 1024 * 1024;
  int G = 32;
  while (G > 1 && wFix + (size_t)G * perB > ws_size) G >>= 1;

  char* ws = (char*)d_ws;
  float* hdr = (float*)ws;

  const long WE = 1024L * 1024;
  unsigned short* WQKh = (unsigned short*)(ws + 65536);  // [2048][1024]
  unsigned short* WQKl = WQKh + 2 * WE;
  unsigned short* Wvh  = WQKl + 2 * WE;
  unsigned short* Wvl  = Wvh + WE;
  unsigned short* Wph  = Wvl + WE;
  unsigned short* Wpl  = Wph + WE;

  const long YB = 524288;  // elements/batch of y arrays ([C][N])
  unsigned short* yqh = Wpl + WE;
  unsigned short* yql = yqh + (long)G * YB;
  unsigned short* ykh = yql + (long)G * YB;
  unsigned short* ykl = ykh + (long)G * YB;
  const long QKBS = 1048576;  // [2048][512] per batch
  unsigned short* QKh = ykl + (long)G * YB;
  unsigned short* QKl = QKh + (long)G * QKBS;
  float* S = (float*)(QKl + (long)G * QKBS);  // [G][1024][1024]

  unsigned short* dout_us = (unsigned short*)d_out;  // per batch: yv hi|lo slot

  dim3 blk(256);
  const int BIG = 1 << 30;

  prep3<<<dim3(4), blk, 0, stream>>>(qg, qb, qm, qv, kg, kb, km, kv, vg, vb, vm, vv, hdr);

  const long W4 = WE / 4;
  convert_w<<<dim3(1024), blk, 0, stream>>>(Wq, WQKh, WQKl, W4);
  convert_w<<<dim3(1024), blk, 0, stream>>>(Wk, WQKh + WE, WQKl + WE, W4);
  convert_w<<<dim3(1024), blk, 0, stream>>>(Wv, Wvh, Wvl, W4);
  convert_w<<<dim3(1024), blk, 0, stream>>>(Wp, Wph, Wpl, W4);

  for (int b0 = 0; b0 < Bb; b0 += G) {
    const float* xg = x + (size_t)b0 * Cc * Nn;

    // 1) BN+ReLU+split: yq,yk -> ws; yv -> d_out slots
    convert_y3<<<dim3(2048), blk, 0, stream>>>(
        xg, hdr, yqh, yql, ykh, ykl, dout_us, b0, (long)G * 131072);

    // 2) [Q;K] = [Wq;Wk] x y: M=2048, N=512, K=1024; BM256, m-fastest (y-panel reuse)
    gemm3p<true, true, 256><<<dim3(8 * 2 * G), dim3(512), 0, stream>>>(
        WQKh, WQKl, Nn, 0L,
        yqh, yql, ykh, ykl, 1024, Nn, YB,
        nullptr, QKh, QKl, Cc, QKBS, Nn, 1.0f, 8, 2);

    // 3) S = Q K^T / 32: M=1024, N=1024, K=512; BM256
    gemm3p<false, false, 256><<<dim3(4 * 4 * G), dim3(512), 0, stream>>>(
        QKh, QKl, Cc, QKBS,
        QKh + 524288, QKl + 524288, nullptr, nullptr, BIG, Cc, QKBS,
        S, nullptr, nullptr, Ee, 1048576L, Cc, 0.03125f, 4, 4);

    // 4) softmax rows -> P hi/lo packed in S
    softmax_rows<<<dim3(G * Ee), blk, 0, stream>>>(S);

    // 5) Vt[c][e] = sum_n yv[c][n] Wv[e][n]: M=512, N=1024, K=1024; BM128
    gemm3p<true, false, 128><<<dim3(4 * 4 * G), dim3(512), 0, stream>>>(
        dout_us + (long)b0 * 1048576, dout_us + (long)b0 * 1048576 + 524288, Nn, 1048576L,
        Wvh, Wvl, nullptr, nullptr, BIG, Nn, 0L,
        nullptr, yqh, yql, Ee, YB, Nn, 1.0f, 4, 4);

    // 6) Ot[c][e] = sum_f Vt[c][f] P[e][f]: M=512, N=1024, K=1024; BM128
    gemm3p<true, false, 128><<<dim3(4 * 4 * G), dim3(512), 0, stream>>>(
        yqh, yql, Ee, YB,
        (unsigned short*)S, (unsigned short*)S + 1024, nullptr, nullptr, BIG,
        2L * Ee, 2097152L,
        nullptr, QKh, QKl, Ee, QKBS, Ee, 1.0f, 4, 4);

    // 7) out[c][n] = sum_e Ot[c][e] Wp[n][e]: M=512, N=1024, K=1024; BM128, f32 out
    gemm3p<false, false, 128><<<dim3(4 * 4 * G), dim3(512), 0, stream>>>(
        QKh, QKl, Ee, QKBS,
        Wph, Wpl, nullptr, nullptr, BIG, Ee, 0L,
        (float*)d_out + (size_t)b0 * Cc * Nn, nullptr, nullptr,
        Nn, (long)Cc * Nn, Ee, 1.0f, 4, 4);
  }
}

// Round 12
// 777.835 us; speedup vs baseline: 1.0836x; 1.0191x over previous
//
#include <hip/hip_runtime.h>
#include <math.h>

#define BN_EPS 1e-5f

namespace {

constexpr int Bb = 32;   // batch
constexpr int Cc = 512;  // channels
constexpr int Nn = 1024; // spatial (H*W)
constexpr int Ee = 1024; // embed

typedef __attribute__((ext_vector_type(8))) short short8;
typedef __attribute__((ext_vector_type(4))) float f32x4;
typedef __attribute__((ext_vector_type(4))) unsigned short ushort4_t;

struct bfpair { unsigned short h, l; };

__device__ __forceinline__ unsigned short bf16_rne(float v) {
  unsigned u = __builtin_bit_cast(unsigned, v);
  unsigned r = u + 0x7FFFu + ((u >> 16) & 1u);
  return (unsigned short)(r >> 16);
}
__device__ __forceinline__ float bf16_to_f(unsigned short h) {
  unsigned u = ((unsigned)h) << 16;
  return __builtin_bit_cast(float, u);
}
__device__ __forceinline__ bfpair split_bf(float v) {
  bfpair p;
  p.h = bf16_rne(v);
  p.l = bf16_rne(v - bf16_to_f(p.h));
  return p;
}

__device__ __forceinline__ void gll16(const void* g, void* l) {
  __builtin_amdgcn_global_load_lds(
      (const __attribute__((address_space(1))) void*)g,
      (__attribute__((address_space(3))) void*)l, 16, 0, 0);
}

// all three BN scale/shift pairs in one launch -> hdr[6][1024]
__global__ __launch_bounds__(256) void prep3(
    const float* __restrict__ qg, const float* __restrict__ qb,
    const float* __restrict__ qm, const float* __restrict__ qv,
    const float* __restrict__ kg, const float* __restrict__ kb,
    const float* __restrict__ km, const float* __restrict__ kv,
    const float* __restrict__ vg, const float* __restrict__ vb,
    const float* __restrict__ vm, const float* __restrict__ vv,
    float* __restrict__ hdr) {
  int i = blockIdx.x * blockDim.x + threadIdx.x;
  if (i < 1024) {
    float inv, sc;
    inv = rsqrtf(qv[i] + BN_EPS); sc = qg[i] * inv;
    hdr[i] = sc;          hdr[1024 + i] = qb[i] - qm[i] * sc;
    inv = rsqrtf(kv[i] + BN_EPS); sc = kg[i] * inv;
    hdr[2048 + i] = sc;   hdr[3072 + i] = kb[i] - km[i] * sc;
    inv = rsqrtf(vv[i] + BN_EPS); sc = vg[i] * inv;
    hdr[4096 + i] = sc;   hdr[5120 + i] = vb[i] - vm[i] * sc;
  }
}

// plain f32 -> hi/lo bf16 split (weights)
__global__ __launch_bounds__(256) void convert_w(
    const float* __restrict__ wsrc, unsigned short* __restrict__ wh,
    unsigned short* __restrict__ wl, long total4) {
  for (long i = (long)blockIdx.x * 256 + threadIdx.x; i < total4; i += (long)gridDim.x * 256) {
    float4 v = ((const float4*)wsrc)[i];
    bfpair p0 = split_bf(v.x), p1 = split_bf(v.y), p2 = split_bf(v.z), p3 = split_bf(v.w);
    ushort4_t hv, lv;
    hv.x = p0.h; hv.y = p1.h; hv.z = p2.h; hv.w = p3.h;
    lv.x = p0.l; lv.y = p1.l; lv.z = p2.l; lv.w = p3.l;
    *(ushort4_t*)&wh[i * 4] = hv;
    *(ushort4_t*)&wl[i * 4] = lv;
  }
}

// One x pass -> yq, yk (ws) and yv (d_out batch slots), all split hi/lo bf16.
__global__ __launch_bounds__(256) void convert_y3(
    const float* __restrict__ x, const float* __restrict__ hdr,
    unsigned short* __restrict__ yqh, unsigned short* __restrict__ yql,
    unsigned short* __restrict__ ykh, unsigned short* __restrict__ ykl,
    unsigned short* __restrict__ dout_us, long b0, long total4) {
  const float* sq = hdr;        const float* tq = hdr + 1024;
  const float* sk = hdr + 2048; const float* tk = hdr + 3072;
  const float* sv = hdr + 4096; const float* tv = hdr + 5120;
  for (long i = (long)blockIdx.x * 256 + threadIdx.x; i < total4; i += (long)gridDim.x * 256) {
    float4 v = ((const float4*)x)[i];
    int n4 = (int)(i & 255);
    float4 a, b;
    ushort4_t hv, lv;
    a = ((const float4*)sq)[n4]; b = ((const float4*)tq)[n4];
    {
      bfpair p0 = split_bf(fmaxf(fmaf(v.x, a.x, b.x), 0.f));
      bfpair p1 = split_bf(fmaxf(fmaf(v.y, a.y, b.y), 0.f));
      bfpair p2 = split_bf(fmaxf(fmaf(v.z, a.z, b.z), 0.f));
      bfpair p3 = split_bf(fmaxf(fmaf(v.w, a.w, b.w), 0.f));
      hv.x = p0.h; hv.y = p1.h; hv.z = p2.h; hv.w = p3.h;
      lv.x = p0.l; lv.y = p1.l; lv.z = p2.l; lv.w = p3.l;
      *(ushort4_t*)&yqh[i * 4] = hv; *(ushort4_t*)&yql[i * 4] = lv;
    }
    a = ((const float4*)sk)[n4]; b = ((const float4*)tk)[n4];
    {
      bfpair p0 = split_bf(fmaxf(fmaf(v.x, a.x, b.x), 0.f));
      bfpair p1 = split_bf(fmaxf(fmaf(v.y, a.y, b.y), 0.f));
      bfpair p2 = split_bf(fmaxf(fmaf(v.z, a.z, b.z), 0.f));
      bfpair p3 = split_bf(fmaxf(fmaf(v.w, a.w, b.w), 0.f));
      hv.x = p0.h; hv.y = p1.h; hv.z = p2.h; hv.w = p3.h;
      lv.x = p0.l; lv.y = p1.l; lv.z = p2.l; lv.w = p3.l;
      *(ushort4_t*)&ykh[i * 4] = hv; *(ushort4_t*)&ykl[i * 4] = lv;
    }
    a = ((const float4*)sv)[n4]; b = ((const float4*)tv)[n4];
    {
      bfpair p0 = split_bf(fmaxf(fmaf(v.x, a.x, b.x), 0.f));
      bfpair p1 = split_bf(fmaxf(fmaf(v.y, a.y, b.y), 0.f));
      bfpair p2 = split_bf(fmaxf(fmaf(v.z, a.z, b.z), 0.f));
      bfpair p3 = split_bf(fmaxf(fmaf(v.w, a.w, b.w), 0.f));
      hv.x = p0.h; hv.y = p1.h; hv.z = p2.h; hv.w = p3.h;
      lv.x = p0.l; lv.y = p1.l; lv.z = p2.l; lv.w = p3.l;
      long g = i >> 17;
      long local = i & 131071;
      unsigned short* slot = dout_us + (b0 + g) * 1048576L;
      *(ushort4_t*)&slot[local * 4] = hv;
      *(ushort4_t*)&slot[524288 + local * 4] = lv;
    }
  }
}

#define MFMA16 __builtin_amdgcn_mfma_f32_16x16x32_bf16

// ---------------------------------------------------------------------------
// 4-phase (m201-style) split-bf16 NT GEMM, BM=256, 512 threads / 8 waves (2x4),
// BK=32, dbuf, mfma 16x16x32.  acc += Ah*Bh + Ah*Bl + Al*Bh.
// Per tile: vmcnt(8)->barrier (buf ready), then 4 phases of
//   {reads (A-pair; ph0 also all B) -> lgkmcnt(0) -> barrier ->
//    stage 1 piece of tile t+2 (safe: rows already consumed) ->
//    setprio 24-MFMA setprio}.
// Reads precede the barrier so ds_read latency hides in barrier wait (fixes
// r10's reads-after-barrier serialization).  vmcnt never drains mid-loop.
// Chunk-XOR swizzle + fragment addressing identical to r9 (0 conflicts).
// ---------------------------------------------------------------------------
template<bool SPLIT, bool MFIRST>
__global__ __launch_bounds__(512, 2) void gemm_ph(
    const unsigned short* __restrict__ Ah_, const unsigned short* __restrict__ Al_,
    long ldA, long bsA,
    const unsigned short* __restrict__ Bh0, const unsigned short* __restrict__ Bl0,
    const unsigned short* __restrict__ Bh1, const unsigned short* __restrict__ Bl1,
    int msel, long ldB, long bsB,
    float* __restrict__ Cf, unsigned short* __restrict__ Chi, unsigned short* __restrict__ Clo,
    long ldC, long bsC, int K, float alpha, int g0, int g1) {
  __shared__ unsigned short sA[2][2][256][32];
  __shared__ unsigned short sB[2][2][256][32];

  const int nb = gridDim.x;
  int f = blockIdx.x;
  if ((nb & 7) == 0) f = (f & 7) * (nb >> 3) + (f >> 3);
  const int i0 = f % g0, i1 = (f / g0) % g1;
  const long zb = f / (g0 * g1);
  const int m0 = (MFIRST ? i0 : i1) * 256;
  const int n0 = (MFIRST ? i1 : i0) * 256;

  const int t = threadIdx.x, lane = t & 63, w = t >> 6;
  const int wr = w >> 2, wc = w & 3, k4 = w & 3;
  const int sr  = lane >> 2;
  const int skc = (((lane & 3) ^ ((lane >> 3) & 3)) * 8);
  const int fr = lane & 15;
  const int kq = ((((lane >> 4) & 3) ^ ((fr >> 1) & 3)) * 8);

  const unsigned short* Bh = (m0 >= msel) ? Bh1 : Bh0;
  const unsigned short* Bl = (m0 >= msel) ? Bl1 : Bl0;

  const unsigned short* a0 = Ah_ + zb * bsA + (long)(m0 + w * 32 + sr) * ldA + skc;
  const unsigned short* a1 = Al_ + zb * bsA + (long)(m0 + w * 32 + sr) * ldA + skc;
  const unsigned short* b0 = Bh + zb * bsB + (long)(n0 + w * 32 + sr) * ldB + skc;
  const unsigned short* b1 = Bl + zb * bsB + (long)(n0 + w * 32 + sr) * ldB + skc;
  const long a16 = 16 * ldA, b16 = 16 * ldB;

  // stage pieces: 2 gll16 each, into buf bf at k-offset ko (elements)
  auto PAH = [&](int bf, long ko) {
    gll16(a0 + ko, &sA[bf][0][w * 32][0]); gll16(a0 + ko + a16, &sA[bf][0][w * 32 + 16][0]);
  };
  auto PAL = [&](int bf, long ko) {
    gll16(a1 + ko, &sA[bf][1][w * 32][0]); gll16(a1 + ko + a16, &sA[bf][1][w * 32 + 16][0]);
  };
  auto PBH = [&](int bf, long ko) {
    gll16(b0 + ko, &sB[bf][0][w * 32][0]); gll16(b0 + ko + b16, &sB[bf][0][w * 32 + 16][0]);
  };
  auto PBL = [&](int bf, long ko) {
    gll16(b1 + ko, &sB[bf][1][w * 32][0]); gll16(b1 + ko + b16, &sB[bf][1][w * 32 + 16][0]);
  };

  f32x4 acc[8][4] = {};
  const int nt = K >> 5;

  // prologue: tiles 0,1 staged whole (8 loads each, in tile order for vmcnt)
  PAH(0, 0);  PAL(0, 0);  PBH(0, 0);  PBL(0, 0);
  PAH(1, 32); PAL(1, 32); PBH(1, 32); PBL(1, 32);

  for (int it = 0; it < nt; ++it) {
    const int c = it & 1;
    const bool st = (it + 2 < nt);
    const long ko = (long)(it + 2) * 32;

    // ---- tile open: counted wait, buf[c] ready ----
    if (it + 1 < nt) asm volatile("s_waitcnt vmcnt(8)" ::: "memory");
    else             asm volatile("s_waitcnt vmcnt(0)" ::: "memory");
    asm volatile("s_barrier" ::: "memory");

    // ================= phase 0 =================
    short8 bh[4], bl[4], ah0, al0, ah1, al1;
#pragma unroll
    for (int j = 0; j < 4; ++j) {
      bh[j] = *(const short8*)&sB[c][0][wc * 64 + j * 16 + fr][kq];
      bl[j] = *(const short8*)&sB[c][1][wc * 64 + j * 16 + fr][kq];
    }
    ah0 = *(const short8*)&sA[c][0][wr * 128 + 0 * 16 + fr][kq];
    al0 = *(const short8*)&sA[c][1][wr * 128 + 0 * 16 + fr][kq];
    ah1 = *(const short8*)&sA[c][0][wr * 128 + 1 * 16 + fr][kq];
    al1 = *(const short8*)&sA[c][1][wr * 128 + 1 * 16 + fr][kq];
    asm volatile("s_waitcnt lgkmcnt(0)" ::: "memory");
    asm volatile("s_barrier" ::: "memory");
    if (st) { if (k4 == 0) PAH(c, ko); else if (k4 == 1) PBL(c, ko); else PBH(c, ko); }
    __builtin_amdgcn_s_setprio(1);
#pragma unroll
    for (int j = 0; j < 4; ++j) {
      acc[0][j] = MFMA16(ah0, bh[j], acc[0][j], 0, 0, 0);
      acc[0][j] = MFMA16(ah0, bl[j], acc[0][j], 0, 0, 0);
      acc[0][j] = MFMA16(al0, bh[j], acc[0][j], 0, 0, 0);
      acc[1][j] = MFMA16(ah1, bh[j], acc[1][j], 0, 0, 0);
      acc[1][j] = MFMA16(ah1, bl[j], acc[1][j], 0, 0, 0);
      acc[1][j] = MFMA16(al1, bh[j], acc[1][j], 0, 0, 0);
    }
    __builtin_amdgcn_s_setprio(0);

    // ================= phase 1 =================
    ah0 = *(const short8*)&sA[c][0][wr * 128 + 2 * 16 + fr][kq];
    al0 = *(const short8*)&sA[c][1][wr * 128 + 2 * 16 + fr][kq];
    ah1 = *(const short8*)&sA[c][0][wr * 128 + 3 * 16 + fr][kq];
    al1 = *(const short8*)&sA[c][1][wr * 128 + 3 * 16 + fr][kq];
    asm volatile("s_waitcnt lgkmcnt(0)" ::: "memory");
    asm volatile("s_barrier" ::: "memory");
    if (st) { if (k4 == 0) PAL(c, ko); else if (k4 == 1) PAH(c, ko); else PBL(c, ko); }
    __builtin_amdgcn_s_setprio(1);
#pragma unroll
    for (int j = 0; j < 4; ++j) {
      acc[2][j] = MFMA16(ah0, bh[j], acc[2][j], 0, 0, 0);
      acc[2][j] = MFMA16(ah0, bl[j], acc[2][j], 0, 0, 0);
      acc[2][j] = MFMA16(al0, bh[j], acc[2][j], 0, 0, 0);
      acc[3][j] = MFMA16(ah1, bh[j], acc[3][j], 0, 0, 0);
      acc[3][j] = MFMA16(ah1, bl[j], acc[3][j], 0, 0, 0);
      acc[3][j] = MFMA16(al1, bh[j], acc[3][j], 0, 0, 0);
    }
    __builtin_amdgcn_s_setprio(0);

    // ================= phase 2 =================
    ah0 = *(const short8*)&sA[c][0][wr * 128 + 4 * 16 + fr][kq];
    al0 = *(const short8*)&sA[c][1][wr * 128 + 4 * 16 + fr][kq];
    ah1 = *(const short8*)&sA[c][0][wr * 128 + 5 * 16 + fr][kq];
    al1 = *(const short8*)&sA[c][1][wr * 128 + 5 * 16 + fr][kq];
    asm volatile("s_waitcnt lgkmcnt(0)" ::: "memory");
    asm volatile("s_barrier" ::: "memory");
    if (st) { if (k4 == 0) PBH(c, ko); else if (k4 == 1) PAL(c, ko); else if (k4 == 2) PAH(c, ko); }
    __builtin_amdgcn_s_setprio(1);
#pragma unroll
    for (int j = 0; j < 4; ++j) {
      acc[4][j] = MFMA16(ah0, bh[j], acc[4][j], 0, 0, 0);
      acc[4][j] = MFMA16(ah0, bl[j], acc[4][j], 0, 0, 0);
      acc[4][j] = MFMA16(al0, bh[j], acc[4][j], 0, 0, 0);
      acc[5][j] = MFMA16(ah1, bh[j], acc[5][j], 0, 0, 0);
      acc[5][j] = MFMA16(ah1, bl[j], acc[5][j], 0, 0, 0);
      acc[5][j] = MFMA16(al1, bh[j], acc[5][j], 0, 0, 0);
    }
    __builtin_amdgcn_s_setprio(0);

    // ================= phase 3 =================
    ah0 = *(const short8*)&sA[c][0][wr * 128 + 6 * 16 + fr][kq];
    al0 = *(const short8*)&sA[c][1][wr * 128 + 6 * 16 + fr][kq];
    ah1 = *(const short8*)&sA[c][0][wr * 128 + 7 * 16 + fr][kq];
    al1 = *(const short8*)&sA[c][1][wr * 128 + 7 * 16 + fr][kq];
    asm volatile("s_waitcnt lgkmcnt(0)" ::: "memory");
    asm volatile("s_barrier" ::: "memory");
    if (st) {
      if (k4 == 0) PBL(c, ko);
      else if (k4 == 1) PBH(c, ko);
      else if (k4 == 2) PAL(c, ko);
      else { PAH(c, ko); PAL(c, ko); }
    }
    __builtin_amdgcn_s_setprio(1);
#pragma unroll
    for (int j = 0; j < 4; ++j) {
      acc[6][j] = MFMA16(ah0, bh[j], acc[6][j], 0, 0, 0);
      acc[6][j] = MFMA16(ah0, bl[j], acc[6][j], 0, 0, 0);
      acc[6][j] = MFMA16(al0, bh[j], acc[6][j], 0, 0, 0);
      acc[7][j] = MFMA16(ah1, bh[j], acc[7][j], 0, 0, 0);
      acc[7][j] = MFMA16(ah1, bl[j], acc[7][j], 0, 0, 0);
      acc[7][j] = MFMA16(al1, bh[j], acc[7][j], 0, 0, 0);
    }
    __builtin_amdgcn_s_setprio(0);
  }

  // epilogue: C/D layout col = lane&15, row = (lane>>4)*4 + reg  [verified m89/m91]
  const int rb = ((lane >> 4) & 3) * 4;
#pragma unroll
  for (int i = 0; i < 8; ++i)
#pragma unroll
    for (int j = 0; j < 4; ++j) {
      long col = n0 + wc * 64 + j * 16 + fr;
#pragma unroll
      for (int v = 0; v < 4; ++v) {
        long row = m0 + wr * 128 + i * 16 + rb + v;
        float val = acc[i][j][v] * alpha;
        long idx = zb * bsC + row * ldC + col;
        if (SPLIT) {
          bfpair p = split_bf(val);
          Chi[idx] = p.h;
          Clo[idx] = p.l;
        } else {
          Cf[idx] = val;
        }
      }
    }
}

// ---------------------------------------------------------------------------
// r9 kernel (validated 731 us): used for the BM128 GEMMs (Vt, Ot, out).
// ---------------------------------------------------------------------------
template<bool SPLIT, bool MFIRST>
__global__ __launch_bounds__(512, 2) void gemm128(
    const unsigned short* __restrict__ Ah, const unsigned short* __restrict__ Al,
    long ldA, long bsA,
    const unsigned short* __restrict__ Bh0, const unsigned short* __restrict__ Bl0,
    int msel, long ldB, long bsB,
    float* __restrict__ Cf, unsigned short* __restrict__ Chi, unsigned short* __restrict__ Clo,
    long ldC, long bsC, int K, float alpha, int g0, int g1) {
  constexpr int WH = 64;
  __shared__ unsigned short sA[2][2][128][32];
  __shared__ unsigned short sB[2][2][256][32];

  const int nb = gridDim.x;
  int f = blockIdx.x;
  if ((nb & 7) == 0) f = (f & 7) * (nb >> 3) + (f >> 3);
  const int i0 = f % g0, i1 = (f / g0) % g1;
  const long zb = f / (g0 * g1);
  const int m0 = (MFIRST ? i0 : i1) * 128;
  const int n0 = (MFIRST ? i1 : i0) * 256;

  const int t = threadIdx.x, lane = t & 63, w = t >> 6;
  const int wr = w >> 2, wc = w & 3;
  const int sr  = lane >> 2;
  const int skc = (((lane & 3) ^ ((lane >> 3) & 3)) * 8);
  const int fr = lane & 15;
  const int kq = ((((lane >> 4) & 3) ^ ((fr >> 1) & 3)) * 8);

  const int aw = w & 3, ahl = w >> 2;
  const unsigned short* a0 =
      (ahl ? Al : Ah) + zb * bsA + (long)(m0 + aw * 32 + sr) * ldA + skc;
  const unsigned short* b0 = Bh0 + zb * bsB + (long)(n0 + w * 32 + sr) * ldB + skc;
  const unsigned short* b1 = Bl0 + zb * bsB + (long)(n0 + w * 32 + sr) * ldB + skc;
  const long a16 = 16 * ldA, b16 = 16 * ldB;

  auto STAGE = [&](int buf) {
    gll16(a0, &sA[buf][ahl][aw * 32][0]);
    gll16(a0 + a16, &sA[buf][ahl][aw * 32 + 16][0]);
    a0 += 32;
    gll16(b0, &sB[buf][0][w * 32][0]);  gll16(b0 + b16, &sB[buf][0][w * 32 + 16][0]);
    gll16(b1, &sB[buf][1][w * 32][0]);  gll16(b1 + b16, &sB[buf][1][w * 32 + 16][0]);
    b0 += 32; b1 += 32;
  };

  f32x4 acc[4][4] = {};
  const int nt = K >> 5;

  STAGE(0);
  STAGE(1);
  int cur = 0;

  for (int it = 0; it < nt; ++it) {
    if (it + 1 < nt) asm volatile("s_waitcnt vmcnt(6)" ::: "memory");
    else             asm volatile("s_waitcnt vmcnt(0)" ::: "memory");
    asm volatile("s_barrier" ::: "memory");

    short8 bh[4], bl[4], ah[4], al[4];
#pragma unroll
    for (int j = 0; j < 4; ++j) {
      bh[j] = *(const short8*)&sB[cur][0][wc * 64 + j * 16 + fr][kq];
      bl[j] = *(const short8*)&sB[cur][1][wc * 64 + j * 16 + fr][kq];
    }
#pragma unroll
    for (int i = 0; i < 4; ++i) {
      ah[i] = *(const short8*)&sA[cur][0][wr * WH + i * 16 + fr][kq];
      al[i] = *(const short8*)&sA[cur][1][wr * WH + i * 16 + fr][kq];
    }
    asm volatile("s_waitcnt lgkmcnt(0)" ::: "memory");
    asm volatile("s_barrier" ::: "memory");
    if (it + 2 < nt) STAGE(cur);
    __builtin_amdgcn_s_setprio(1);
#pragma unroll
    for (int i = 0; i < 4; ++i)
#pragma unroll
      for (int j = 0; j < 4; ++j) {
        acc[i][j] = MFMA16(ah[i], bh[j], acc[i][j], 0, 0, 0);
        acc[i][j] = MFMA16(ah[i], bl[j], acc[i][j], 0, 0, 0);
        acc[i][j] = MFMA16(al[i], bh[j], acc[i][j], 0, 0, 0);
      }
    __builtin_amdgcn_s_setprio(0);
    cur ^= 1;
  }

  const int rb = ((lane >> 4) & 3) * 4;
#pragma unroll
  for (int i = 0; i < 4; ++i)
#pragma unroll
    for (int j = 0; j < 4; ++j) {
      long col = n0 + wc * 64 + j * 16 + fr;
#pragma unroll
      for (int v = 0; v < 4; ++v) {
        long row = m0 + wr * WH + i * 16 + rb + v;
        float val = acc[i][j][v] * alpha;
        long idx = zb * bsC + row * ldC + col;
        if (SPLIT) {
          bfpair p = split_bf(val);
          Chi[idx] = p.h;
          Clo[idx] = p.l;
        } else {
          Cf[idx] = val;
        }
      }
    }
}

// softmax over rows of 1024 f32, writes P split as hi[1024]|lo[1024] ushorts in place.
__global__ __launch_bounds__(256) void softmax_rows(float* __restrict__ S) {
  long row = blockIdx.x;
  float* p = S + row * 1024;
  int t = threadIdx.x;
  float4 v = *(float4*)(p + 4 * t);
  float mx = fmaxf(fmaxf(v.x, v.y), fmaxf(v.z, v.w));
#pragma unroll
  for (int i = 1; i < 64; i <<= 1) mx = fmaxf(mx, __shfl_xor(mx, i));
  __shared__ float redm[4];
  __shared__ float reds[4];
  int wave = t >> 6, lane = t & 63;
  if (lane == 0) redm[wave] = mx;
  __syncthreads();
  mx = fmaxf(fmaxf(redm[0], redm[1]), fmaxf(redm[2], redm[3]));
  float e0 = expf(v.x - mx), e1 = expf(v.y - mx);
  float e2 = expf(v.z - mx), e3 = expf(v.w - mx);
  float sum = (e0 + e1) + (e2 + e3);
#pragma unroll
  for (int i = 1; i < 64; i <<= 1) sum += __shfl_xor(sum, i);
  if (lane == 0) reds[wave] = sum;
  __syncthreads();
  sum = (reds[0] + reds[1]) + (reds[2] + reds[3]);
  float inv = 1.0f / sum;
  bfpair p0 = split_bf(e0 * inv), p1 = split_bf(e1 * inv);
  bfpair p2 = split_bf(e2 * inv), p3 = split_bf(e3 * inv);
  ushort4_t hv, lv;
  hv.x = p0.h; hv.y = p1.h; hv.z = p2.h; hv.w = p3.h;
  lv.x = p0.l; lv.y = p1.l; lv.z = p2.l; lv.w = p3.l;
  unsigned short* ph = (unsigned short*)p;
  *(ushort4_t*)&ph[4 * t] = hv;
  *(ushort4_t*)&ph[1024 + 4 * t] = lv;
}

}  // namespace

extern "C" void kernel_launch(void* const* d_in, const int* in_sizes, int n_in,
                              void* d_out, int out_size, void* d_ws, size_t ws_size,
                              hipStream_t stream) {
  const float* x  = (const float*)d_in[0];
  const float* qg = (const float*)d_in[1];
  const float* qb = (const float*)d_in[2];
  const float* qm = (const float*)d_in[3];
  const float* qv = (const float*)d_in[4];
  const float* kg = (const float*)d_in[5];
  const float* kb = (const float*)d_in[6];
  const float* km = (const float*)d_in[7];
  const float* kv = (const float*)d_in[8];
  const float* vg = (const float*)d_in[9];
  const float* vb = (const float*)d_in[10];
  const float* vm = (const float*)d_in[11];
  const float* vv = (const float*)d_in[12];
  const float* Wq = (const float*)d_in[13];
  const float* Wk = (const float*)d_in[14];
  const float* Wv = (const float*)d_in[15];
  const float* Wp = (const float*)d_in[16];

  // ---- workspace (r9 layout) ----
  const size_t wFix = 65536 + 16UL * 1024 * 1024;
  const size_t perB = 12UL * 1024 * 1024;
  int G = 32;
  while (G > 1 && wFix + (size_t)G * perB > ws_size) G >>= 1;

  char* ws = (char*)d_ws;
  float* hdr = (float*)ws;

  const long WE = 1024L * 1024;
  unsigned short* WQKh = (unsigned short*)(ws + 65536);  // [2048][1024]
  unsigned short* WQKl = WQKh + 2 * WE;
  unsigned short* Wvh  = WQKl + 2 * WE;
  unsigned short* Wvl  = Wvh + WE;
  unsigned short* Wph  = Wvl + WE;
  unsigned short* Wpl  = Wph + WE;

  const long YB = 524288;
  unsigned short* yqh = Wpl + WE;
  unsigned short* yql = yqh + (long)G * YB;
  unsigned short* ykh = yql + (long)G * YB;
  unsigned short* ykl = ykh + (long)G * YB;
  const long QKBS = 1048576;
  unsigned short* QKh = ykl + (long)G * YB;
  unsigned short* QKl = QKh + (long)G * QKBS;
  float* S = (float*)(QKl + (long)G * QKBS);

  unsigned short* dout_us = (unsigned short*)d_out;

  dim3 blk(256);
  const int BIG = 1 << 30;

  prep3<<<dim3(4), blk, 0, stream>>>(qg, qb, qm, qv, kg, kb, km, kv, vg, vb, vm, vv, hdr);

  const long W4 = WE / 4;
  convert_w<<<dim3(1024), blk, 0, stream>>>(Wq, WQKh, WQKl, W4);
  convert_w<<<dim3(1024), blk, 0, stream>>>(Wk, WQKh + WE, WQKl + WE, W4);
  convert_w<<<dim3(1024), blk, 0, stream>>>(Wv, Wvh, Wvl, W4);
  convert_w<<<dim3(1024), blk, 0, stream>>>(Wp, Wph, Wpl, W4);

  for (int b0 = 0; b0 < Bb; b0 += G) {
    const float* xg = x + (size_t)b0 * Cc * Nn;

    // 1) BN+ReLU+split: yq,yk -> ws; yv -> d_out slots
    convert_y3<<<dim3(2048), blk, 0, stream>>>(
        xg, hdr, yqh, yql, ykh, ykl, dout_us, b0, (long)G * 131072);

    // 2) [Q;K] = [Wq;Wk] x y: M=2048, N=512, K=1024; phased BM256, m-fastest
    gemm_ph<true, true><<<dim3(8 * 2 * G), dim3(512), 0, stream>>>(
        WQKh, WQKl, Nn, 0L,
        yqh, yql, ykh, ykl, 1024, Nn, YB,
        nullptr, QKh, QKl, Cc, QKBS, Nn, 1.0f, 8, 2);

    // 3) S = Q K^T / 32: M=1024, N=1024, K=512; phased BM256
    gemm_ph<false, false><<<dim3(4 * 4 * G), dim3(512), 0, stream>>>(
        QKh, QKl, Cc, QKBS,
        QKh + 524288, QKl + 524288, nullptr, nullptr, BIG, Cc, QKBS,
        S, nullptr, nullptr, Ee, 1048576L, Cc, 0.03125f, 4, 4);

    // 4) softmax rows -> P hi/lo packed in S
    softmax_rows<<<dim3(G * Ee), blk, 0, stream>>>(S);

    // 5) Vt[c][e] = sum_n yv[c][n] Wv[e][n]: M=512, N=1024, K=1024; r9 BM128
    gemm128<true, false><<<dim3(4 * 4 * G), dim3(512), 0, stream>>>(
        dout_us + (long)b0 * 1048576, dout_us + (long)b0 * 1048576 + 524288, Nn, 1048576L,
        Wvh, Wvl, BIG, Nn, 0L,
        nullptr, yqh, yql, Ee, YB, Nn, 1.0f, 4, 4);

    // 6) Ot[c][e] = sum_f Vt[c][f] P[e][f]: M=512, N=1024, K=1024; r9 BM128
    gemm128<true, false><<<dim3(4 * 4 * G), dim3(512), 0, stream>>>(
        yqh, yql, Ee, YB,
        (unsigned short*)S, (unsigned short*)S + 1024, BIG,
        2L * Ee, 2097152L,
        nullptr, QKh, QKl, Ee, QKBS, Ee, 1.0f, 4, 4);

    // 7) out[c][n] = sum_e Ot[c][e] Wp[n][e]: M=512, N=1024, K=1024; r9 BM128
    gemm128<false, false><<<dim3(4 * 4 * G), dim3(512), 0, stream>>>(
        QKh, QKl, Ee, QKBS,
        Wph, Wpl, BIG, Ee, 0L,
        (float*)d_out + (size_t)b0 * Cc * Nn, nullptr, nullptr,
        Nn, (long)Cc * Nn, Ee, 1.0f, 4, 4);
  }
}

// Round 13
// 765.329 us; speedup vs baseline: 1.1013x; 1.0163x over previous
//
#include <hip/hip_runtime.h>
#include <math.h>

#define BN_EPS 1e-5f

namespace {

constexpr int Bb = 32;   // batch
constexpr int Cc = 512;  // channels
constexpr int Nn = 1024; // spatial (H*W)
constexpr int Ee = 1024; // embed

typedef __attribute__((ext_vector_type(8))) short short8;
typedef __attribute__((ext_vector_type(4))) float f32x4;
typedef __attribute__((ext_vector_type(4))) unsigned short ushort4_t;

struct bfpair { unsigned short h, l; };

__device__ __forceinline__ unsigned short bf16_rne(float v) {
  unsigned u = __builtin_bit_cast(unsigned, v);
  unsigned r = u + 0x7FFFu + ((u >> 16) & 1u);
  return (unsigned short)(r >> 16);
}
__device__ __forceinline__ float bf16_to_f(unsigned short h) {
  unsigned u = ((unsigned)h) << 16;
  return __builtin_bit_cast(float, u);
}
__device__ __forceinline__ bfpair split_bf(float v) {
  bfpair p;
  p.h = bf16_rne(v);
  p.l = bf16_rne(v - bf16_to_f(p.h));
  return p;
}

__device__ __forceinline__ void gll16(const void* g, void* l) {
  __builtin_amdgcn_global_load_lds(
      (const __attribute__((address_space(1))) void*)g,
      (__attribute__((address_space(3))) void*)l, 16, 0, 0);
}

// all three BN scale/shift pairs in one launch -> hdr[6][1024]
__global__ __launch_bounds__(256) void prep3(
    const float* __restrict__ qg, const float* __restrict__ qb,
    const float* __restrict__ qm, const float* __restrict__ qv,
    const float* __restrict__ kg, const float* __restrict__ kb,
    const float* __restrict__ km, const float* __restrict__ kv,
    const float* __restrict__ vg, const float* __restrict__ vb,
    const float* __restrict__ vm, const float* __restrict__ vv,
    float* __restrict__ hdr) {
  int i = blockIdx.x * blockDim.x + threadIdx.x;
  if (i < 1024) {
    float inv, sc;
    inv = rsqrtf(qv[i] + BN_EPS); sc = qg[i] * inv;
    hdr[i] = sc;          hdr[1024 + i] = qb[i] - qm[i] * sc;
    inv = rsqrtf(kv[i] + BN_EPS); sc = kg[i] * inv;
    hdr[2048 + i] = sc;   hdr[3072 + i] = kb[i] - km[i] * sc;
    inv = rsqrtf(vv[i] + BN_EPS); sc = vg[i] * inv;
    hdr[4096 + i] = sc;   hdr[5120 + i] = vb[i] - vm[i] * sc;
  }
}

// plain f32 -> hi/lo bf16 split (weights)
__global__ __launch_bounds__(256) void convert_w(
    const float* __restrict__ wsrc, unsigned short* __restrict__ wh,
    unsigned short* __restrict__ wl, long total4) {
  for (long i = (long)blockIdx.x * 256 + threadIdx.x; i < total4; i += (long)gridDim.x * 256) {
    float4 v = ((const float4*)wsrc)[i];
    bfpair p0 = split_bf(v.x), p1 = split_bf(v.y), p2 = split_bf(v.z), p3 = split_bf(v.w);
    ushort4_t hv, lv;
    hv.x = p0.h; hv.y = p1.h; hv.z = p2.h; hv.w = p3.h;
    lv.x = p0.l; lv.y = p1.l; lv.z = p2.l; lv.w = p3.l;
    *(ushort4_t*)&wh[i * 4] = hv;
    *(ushort4_t*)&wl[i * 4] = lv;
  }
}

// One x pass -> yq, yk (ws) and yv (d_out batch slots), all split hi/lo bf16.
__global__ __launch_bounds__(256) void convert_y3(
    const float* __restrict__ x, const float* __restrict__ hdr,
    unsigned short* __restrict__ yqh, unsigned short* __restrict__ yql,
    unsigned short* __restrict__ ykh, unsigned short* __restrict__ ykl,
    unsigned short* __restrict__ dout_us, long b0, long total4) {
  const float* sq = hdr;        const float* tq = hdr + 1024;
  const float* sk = hdr + 2048; const float* tk = hdr + 3072;
  const float* sv = hdr + 4096; const float* tv = hdr + 5120;
  for (long i = (long)blockIdx.x * 256 + threadIdx.x; i < total4; i += (long)gridDim.x * 256) {
    float4 v = ((const float4*)x)[i];
    int n4 = (int)(i & 255);
    float4 a, b;
    ushort4_t hv, lv;
    a = ((const float4*)sq)[n4]; b = ((const float4*)tq)[n4];
    {
      bfpair p0 = split_bf(fmaxf(fmaf(v.x, a.x, b.x), 0.f));
      bfpair p1 = split_bf(fmaxf(fmaf(v.y, a.y, b.y), 0.f));
      bfpair p2 = split_bf(fmaxf(fmaf(v.z, a.z, b.z), 0.f));
      bfpair p3 = split_bf(fmaxf(fmaf(v.w, a.w, b.w), 0.f));
      hv.x = p0.h; hv.y = p1.h; hv.z = p2.h; hv.w = p3.h;
      lv.x = p0.l; lv.y = p1.l; lv.z = p2.l; lv.w = p3.l;
      *(ushort4_t*)&yqh[i * 4] = hv; *(ushort4_t*)&yql[i * 4] = lv;
    }
    a = ((const float4*)sk)[n4]; b = ((const float4*)tk)[n4];
    {
      bfpair p0 = split_bf(fmaxf(fmaf(v.x, a.x, b.x), 0.f));
      bfpair p1 = split_bf(fmaxf(fmaf(v.y, a.y, b.y), 0.f));
      bfpair p2 = split_bf(fmaxf(fmaf(v.z, a.z, b.z), 0.f));
      bfpair p3 = split_bf(fmaxf(fmaf(v.w, a.w, b.w), 0.f));
      hv.x = p0.h; hv.y = p1.h; hv.z = p2.h; hv.w = p3.h;
      lv.x = p0.l; lv.y = p1.l; lv.z = p2.l; lv.w = p3.l;
      *(ushort4_t*)&ykh[i * 4] = hv; *(ushort4_t*)&ykl[i * 4] = lv;
    }
    a = ((const float4*)sv)[n4]; b = ((const float4*)tv)[n4];
    {
      bfpair p0 = split_bf(fmaxf(fmaf(v.x, a.x, b.x), 0.f));
      bfpair p1 = split_bf(fmaxf(fmaf(v.y, a.y, b.y), 0.f));
      bfpair p2 = split_bf(fmaxf(fmaf(v.z, a.z, b.z), 0.f));
      bfpair p3 = split_bf(fmaxf(fmaf(v.w, a.w, b.w), 0.f));
      hv.x = p0.h; hv.y = p1.h; hv.z = p2.h; hv.w = p3.h;
      lv.x = p0.l; lv.y = p1.l; lv.z = p2.l; lv.w = p3.l;
      long g = i >> 17;
      long local = i & 131071;
      unsigned short* slot = dout_us + (b0 + g) * 1048576L;
      *(ushort4_t*)&slot[local * 4] = hv;
      *(ushort4_t*)&slot[524288 + local * 4] = lv;
    }
  }
}

#define MFMA16 __builtin_amdgcn_mfma_f32_16x16x32_bf16

// ---------------------------------------------------------------------------
// Pipelined split-bf16 NT GEMM, 512 threads / 8 waves (2x4), BK=32,
// mfma 16x16x32.  acc += Ah*Bh + Ah*Bl + Al*Bh.
// r13 schedule: 1-DEEP prefetch, ONE barrier per tile, no lgkm fences.
//   prologue STAGE(tile0 -> buf0)
//   per tile: vmcnt(0) [free: loads issued a full tile ago] -> s_barrier
//             -> STAGE(t+1 -> buf^1) -> ds_reads(buf) -> MFMA.
// Safety: a wave past the barrier has issued all prev-tile MFMAs, whose
// operand interlocks guarantee its buf^1 ds_reads completed -> STAGE into
// buf^1 races nothing.  Per-wave vmcnt drain before the barrier makes all
// waves' tile-t gll16 writes visible after it.
// BM=256: wave tile 128x64, LDS 128 KiB dbuf; A reads split in 2 halves to
// cap registers (no fences between halves - compiler interleaves).
// BM=128: wave tile 64x64, LDS 96 KiB dbuf.
// Chunk-XOR LDS swizzle as validated r5-r9 (0 conflicts).
// B operand selected by m0 (>= msel -> B1) for stacked-[Wq;Wk] projection.
// ---------------------------------------------------------------------------
template<bool SPLIT, bool MFIRST, int BM>
__global__ __launch_bounds__(512, 2) void gemm3p(
    const unsigned short* __restrict__ Ah, const unsigned short* __restrict__ Al,
    long ldA, long bsA,
    const unsigned short* __restrict__ Bh0, const unsigned short* __restrict__ Bl0,
    const unsigned short* __restrict__ Bh1, const unsigned short* __restrict__ Bl1,
    int msel, long ldB, long bsB,
    float* __restrict__ Cf, unsigned short* __restrict__ Chi, unsigned short* __restrict__ Clo,
    long ldC, long bsC, int K, float alpha, int g0, int g1) {
  constexpr int WH = BM / 2;   // wave tile rows
  constexpr int AF = WH / 16;  // A fragments per wave (8 or 4)
  __shared__ unsigned short sA[2][2][BM][32];
  __shared__ unsigned short sB[2][2][256][32];

  const int nb = gridDim.x;
  int f = blockIdx.x;
  if ((nb & 7) == 0) f = (f & 7) * (nb >> 3) + (f >> 3);  // XCD-chunked swizzle
  const int i0 = f % g0, i1 = (f / g0) % g1;
  const long zb = f / (g0 * g1);
  const int m0 = (MFIRST ? i0 : i1) * BM;
  const int n0 = (MFIRST ? i1 : i0) * 256;

  const int t = threadIdx.x, lane = t & 63, w = t >> 6;  // w: 0..7
  const int wr = w >> 2, wc = w & 3;                     // wave tile (wr, wc)
  const int sr  = lane >> 2;
  const int skc = (((lane & 3) ^ ((lane >> 3) & 3)) * 8);      // permuted global col
  const int fr = lane & 15;
  const int kq = ((((lane >> 4) & 3) ^ ((fr >> 1) & 3)) * 8);  // swizzled read col

  const unsigned short* Bh = (m0 >= msel) ? Bh1 : Bh0;
  const unsigned short* Bl = (m0 >= msel) ? Bl1 : Bl0;

  // staging pointers
  const int aw = w & 3, ahl = w >> 2;  // BM==128 mapping
  const unsigned short* a0;
  const unsigned short* a1 = nullptr;
  if (BM == 256) {
    a0 = Ah + zb * bsA + (long)(m0 + w * 32 + sr) * ldA + skc;
    a1 = Al + zb * bsA + (long)(m0 + w * 32 + sr) * ldA + skc;
  } else {
    a0 = (ahl ? Al : Ah) + zb * bsA + (long)(m0 + aw * 32 + sr) * ldA + skc;
  }
  const unsigned short* b0 = Bh + zb * bsB + (long)(n0 + w * 32 + sr) * ldB + skc;
  const unsigned short* b1 = Bl + zb * bsB + (long)(n0 + w * 32 + sr) * ldB + skc;
  const long a16 = 16 * ldA, b16 = 16 * ldB;

  auto STAGE = [&](int buf) {
    if constexpr (BM == 256) {
      gll16(a0, &sA[buf][0][w * 32][0]);  gll16(a0 + a16, &sA[buf][0][w * 32 + 16][0]);
      gll16(a1, &sA[buf][1][w * 32][0]);  gll16(a1 + a16, &sA[buf][1][w * 32 + 16][0]);
      a0 += 32; a1 += 32;
    } else {
      gll16(a0, &sA[buf][ahl][aw * 32][0]);
      gll16(a0 + a16, &sA[buf][ahl][aw * 32 + 16][0]);
      a0 += 32;
    }
    gll16(b0, &sB[buf][0][w * 32][0]);  gll16(b0 + b16, &sB[buf][0][w * 32 + 16][0]);
    gll16(b1, &sB[buf][1][w * 32][0]);  gll16(b1 + b16, &sB[buf][1][w * 32 + 16][0]);
    b0 += 32; b1 += 32;
  };

  f32x4 acc[AF][4] = {};
  const int nt = K >> 5;

  STAGE(0);           // 1-deep prologue: tile 0 only
  int cur = 0;

  for (int it = 0; it < nt; ++it) {
    // tile t's loads were issued one full tile ago -> drain is ~free
    asm volatile("s_waitcnt vmcnt(0)" ::: "memory");
    asm volatile("s_barrier" ::: "memory");   // buf[cur] staged & visible;
                                              // buf^1 reads all consumed
    if (it + 1 < nt) STAGE(cur ^ 1);          // race-free (see header)

    short8 bh[4], bl[4], ah[4], al[4];
#pragma unroll
    for (int j = 0; j < 4; ++j) {
      bh[j] = *(const short8*)&sB[cur][0][wc * 64 + j * 16 + fr][kq];
      bl[j] = *(const short8*)&sB[cur][1][wc * 64 + j * 16 + fr][kq];
    }
#pragma unroll
    for (int i = 0; i < 4; ++i) {
      ah[i] = *(const short8*)&sA[cur][0][wr * WH + i * 16 + fr][kq];
      al[i] = *(const short8*)&sA[cur][1][wr * WH + i * 16 + fr][kq];
    }
    __builtin_amdgcn_s_setprio(1);
#pragma unroll
    for (int i = 0; i < 4; ++i)
#pragma unroll
      for (int j = 0; j < 4; ++j) {
        acc[i][j] = MFMA16(ah[i], bh[j], acc[i][j], 0, 0, 0);
        acc[i][j] = MFMA16(ah[i], bl[j], acc[i][j], 0, 0, 0);
        acc[i][j] = MFMA16(al[i], bh[j], acc[i][j], 0, 0, 0);
      }
    __builtin_amdgcn_s_setprio(0);

    if constexpr (BM == 256) {
      // A half 2 (reuse regs); compiler inserts partial lgkm waits
#pragma unroll
      for (int i = 0; i < 4; ++i) {
        ah[i] = *(const short8*)&sA[cur][0][wr * WH + (i + 4) * 16 + fr][kq];
        al[i] = *(const short8*)&sA[cur][1][wr * WH + (i + 4) * 16 + fr][kq];
      }
      __builtin_amdgcn_s_setprio(1);
#pragma unroll
      for (int i = 0; i < 4; ++i)
#pragma unroll
        for (int j = 0; j < 4; ++j) {
          acc[i + 4][j] = MFMA16(ah[i], bh[j], acc[i + 4][j], 0, 0, 0);
          acc[i + 4][j] = MFMA16(ah[i], bl[j], acc[i + 4][j], 0, 0, 0);
          acc[i + 4][j] = MFMA16(al[i], bh[j], acc[i + 4][j], 0, 0, 0);
        }
      __builtin_amdgcn_s_setprio(0);
    }
    cur ^= 1;
  }

  // epilogue: C/D layout col = lane&15, row = (lane>>4)*4 + reg  [verified m89/m91]
  const int rb = ((lane >> 4) & 3) * 4;
#pragma unroll
  for (int i = 0; i < AF; ++i)
#pragma unroll
    for (int j = 0; j < 4; ++j) {
      long col = n0 + wc * 64 + j * 16 + fr;
#pragma unroll
      for (int v = 0; v < 4; ++v) {
        long row = m0 + wr * WH + i * 16 + rb + v;
        float val = acc[i][j][v] * alpha;
        long idx = zb * bsC + row * ldC + col;
        if (SPLIT) {
          bfpair p = split_bf(val);
          Chi[idx] = p.h;
          Clo[idx] = p.l;
        } else {
          Cf[idx] = val;
        }
      }
    }
}

// softmax over rows of 1024 f32, writes P split as hi[1024]|lo[1024] ushorts in place.
__global__ __launch_bounds__(256) void softmax_rows(float* __restrict__ S) {
  long row = blockIdx.x;
  float* p = S + row * 1024;
  int t = threadIdx.x;
  float4 v = *(float4*)(p + 4 * t);
  float mx = fmaxf(fmaxf(v.x, v.y), fmaxf(v.z, v.w));
#pragma unroll
  for (int i = 1; i < 64; i <<= 1) mx = fmaxf(mx, __shfl_xor(mx, i));
  __shared__ float redm[4];
  __shared__ float reds[4];
  int wave = t >> 6, lane = t & 63;
  if (lane == 0) redm[wave] = mx;
  __syncthreads();
  mx = fmaxf(fmaxf(redm[0], redm[1]), fmaxf(redm[2], redm[3]));
  float e0 = expf(v.x - mx), e1 = expf(v.y - mx);
  float e2 = expf(v.z - mx), e3 = expf(v.w - mx);
  float sum = (e0 + e1) + (e2 + e3);
#pragma unroll
  for (int i = 1; i < 64; i <<= 1) sum += __shfl_xor(sum, i);
  if (lane == 0) reds[wave] = sum;
  __syncthreads();
  sum = (reds[0] + reds[1]) + (reds[2] + reds[3]);
  float inv = 1.0f / sum;
  bfpair p0 = split_bf(e0 * inv), p1 = split_bf(e1 * inv);
  bfpair p2 = split_bf(e2 * inv), p3 = split_bf(e3 * inv);
  ushort4_t hv, lv;
  hv.x = p0.h; hv.y = p1.h; hv.z = p2.h; hv.w = p3.h;
  lv.x = p0.l; lv.y = p1.l; lv.z = p2.l; lv.w = p3.l;
  unsigned short* ph = (unsigned short*)p;
  *(ushort4_t*)&ph[4 * t] = hv;
  *(ushort4_t*)&ph[1024 + 4 * t] = lv;
}

}  // namespace

extern "C" void kernel_launch(void* const* d_in, const int* in_sizes, int n_in,
                              void* d_out, int out_size, void* d_ws, size_t ws_size,
                              hipStream_t stream) {
  const float* x  = (const float*)d_in[0];
  const float* qg = (const float*)d_in[1];
  const float* qb = (const float*)d_in[2];
  const float* qm = (const float*)d_in[3];
  const float* qv = (const float*)d_in[4];
  const float* kg = (const float*)d_in[5];
  const float* kb = (const float*)d_in[6];
  const float* km = (const float*)d_in[7];
  const float* kv = (const float*)d_in[8];
  const float* vg = (const float*)d_in[9];
  const float* vb = (const float*)d_in[10];
  const float* vm = (const float*)d_in[11];
  const float* vv = (const float*)d_in[12];
  const float* Wq = (const float*)d_in[13];
  const float* Wk = (const float*)d_in[14];
  const float* Wv = (const float*)d_in[15];
  const float* Wp = (const float*)d_in[16];

  // ---- workspace (r9 layout) ----
  const size_t wFix = 65536 + 16UL * 1024 * 1024;
  const size_t perB = 12UL * 1024 * 1024;
  int G = 32;
  while (G > 1 && wFix + (size_t)G * perB > ws_size) G >>= 1;

  char* ws = (char*)d_ws;
  float* hdr = (float*)ws;

  const long WE = 1024L * 1024;
  unsigned short* WQKh = (unsigned short*)(ws + 65536);  // [2048][1024]
  unsigned short* WQKl = WQKh + 2 * WE;
  unsigned short* Wvh  = WQKl + 2 * WE;
  unsigned short* Wvl  = Wvh + WE;
  unsigned short* Wph  = Wvl + WE;
  unsigned short* Wpl  = Wph + WE;

  const long YB = 524288;
  unsigned short* yqh = Wpl + WE;
  unsigned short* yql = yqh + (long)G * YB;
  unsigned short* ykh = yql + (long)G * YB;
  unsigned short* ykl = ykh + (long)G * YB;
  const long QKBS = 1048576;
  unsigned short* QKh = ykl + (long)G * YB;
  unsigned short* QKl = QKh + (long)G * QKBS;
  float* S = (float*)(QKl + (long)G * QKBS);

  unsigned short* dout_us = (unsigned short*)d_out;

  dim3 blk(256);
  const int BIG = 1 << 30;

  prep3<<<dim3(4), blk, 0, stream>>>(qg, qb, qm, qv, kg, kb, km, kv, vg, vb, vm, vv, hdr);

  const long W4 = WE / 4;
  convert_w<<<dim3(1024), blk, 0, stream>>>(Wq, WQKh, WQKl, W4);
  convert_w<<<dim3(1024), blk, 0, stream>>>(Wk, WQKh + WE, WQKl + WE, W4);
  convert_w<<<dim3(1024), blk, 0, stream>>>(Wv, Wvh, Wvl, W4);
  convert_w<<<dim3(1024), blk, 0, stream>>>(Wp, Wph, Wpl, W4);

  for (int b0 = 0; b0 < Bb; b0 += G) {
    const float* xg = x + (size_t)b0 * Cc * Nn;

    // 1) BN+ReLU+split: yq,yk -> ws; yv -> d_out slots
    convert_y3<<<dim3(2048), blk, 0, stream>>>(
        xg, hdr, yqh, yql, ykh, ykl, dout_us, b0, (long)G * 131072);

    // 2) [Q;K] = [Wq;Wk] x y: M=2048, N=512, K=1024; BM256, m-fastest
    gemm3p<true, true, 256><<<dim3(8 * 2 * G), dim3(512), 0, stream>>>(
        WQKh, WQKl, Nn, 0L,
        yqh, yql, ykh, ykl, 1024, Nn, YB,
        nullptr, QKh, QKl, Cc, QKBS, Nn, 1.0f, 8, 2);

    // 3) S = Q K^T / 32: M=1024, N=1024, K=512; BM256
    gemm3p<false, false, 256><<<dim3(4 * 4 * G), dim3(512), 0, stream>>>(
        QKh, QKl, Cc, QKBS,
        QKh + 524288, QKl + 524288, nullptr, nullptr, BIG, Cc, QKBS,
        S, nullptr, nullptr, Ee, 1048576L, Cc, 0.03125f, 4, 4);

    // 4) softmax rows -> P hi/lo packed in S
    softmax_rows<<<dim3(G * Ee), blk, 0, stream>>>(S);

    // 5) Vt[c][e] = sum_n yv[c][n] Wv[e][n]: M=512, N=1024, K=1024; BM128
    gemm3p<true, false, 128><<<dim3(4 * 4 * G), dim3(512), 0, stream>>>(
        dout_us + (long)b0 * 1048576, dout_us + (long)b0 * 1048576 + 524288, Nn, 1048576L,
        Wvh, Wvl, nullptr, nullptr, BIG, Nn, 0L,
        nullptr, yqh, yql, Ee, YB, Nn, 1.0f, 4, 4);

    // 6) Ot[c][e] = sum_f Vt[c][f] P[e][f]: M=512, N=1024, K=1024; BM128
    gemm3p<true, false, 128><<<dim3(4 * 4 * G), dim3(512), 0, stream>>>(
        yqh, yql, Ee, YB,
        (unsigned short*)S, (unsigned short*)S + 1024, nullptr, nullptr, BIG,
        2L * Ee, 2097152L,
        nullptr, QKh, QKl, Ee, QKBS, Ee, 1.0f, 4, 4);

    // 7) out[c][n] = sum_e Ot[c][e] Wp[n][e]: M=512, N=1024, K=1024; BM128, f32 out
    gemm3p<false, false, 128><<<dim3(4 * 4 * G), dim3(512), 0, stream>>>(
        QKh, QKl, Ee, QKBS,
        Wph, Wpl, nullptr, nullptr, BIG, Ee, 0L,
        (float*)d_out + (size_t)b0 * Cc * Nn, nullptr, nullptr,
        Nn, (long)Cc * Nn, Ee, 1.0f, 4, 4);
  }
}